// Round 16
// baseline (751.274 us; speedup 1.0000x reference)
//
#include <hip/hip_runtime.h>
#include <hip/hip_bf16.h>
#include <stdint.h>

#define N_NODES 100000
#define MT      782          // 128-row tiles (k3)
#define NS256   391          // 256-row stripes (k1,k2)
#define MPAD    (MT*128)     // 100096 = 391*256
#define IN_DIM  2048
#define HID     512
#define OUTD    128
#define NG      512
#define NPAD    768          // k1 padded N (3 x 256)
#define LOG2F_  0.69314718055994531f

typedef __attribute__((ext_vector_type(4))) float f32x4;
typedef __attribute__((ext_vector_type(8))) short bf16x8;

typedef const __attribute__((address_space(1))) unsigned int gas_u32;
typedef __attribute__((address_space(3))) unsigned int las_u32;

__device__ __forceinline__ void gload_lds16(const void* g, void* lds) {
  __builtin_amdgcn_global_load_lds((gas_u32*)g, (las_u32*)lds, 16, 0, 0);
}

__device__ __forceinline__ short f2bf(float f) {   // manual RNE
  unsigned u = __builtin_bit_cast(unsigned, f);
  u = (u + 0x7fffu + ((u >> 16) & 1u)) >> 16;
  return (short)u;
}
__device__ __forceinline__ short f2bf_hw(float f) {
  __hip_bfloat16 h = __float2bfloat16(f);
  return __builtin_bit_cast(short, h);
}
__device__ __forceinline__ float bf2f(short s) {
  unsigned u = ((unsigned)(unsigned short)s) << 16;
  return __builtin_bit_cast(float, u);
}

__device__ __forceinline__ f32x4 mfma16(bf16x8 a, bf16x8 b, f32x4 c) {
  return __builtin_amdgcn_mfma_f32_16x16x32_bf16(a, b, c, 0, 0, 0);
}

// ---------------- prep (coalesced reads: consecutive threads -> consecutive n)
// wcatS: k-slot [k/8][NPAD][e] ([W1|Wj] cols 0..639, zero-pad 640..767).
// w2tS : k-slot [k/8][512][e].  w3t: row-major [n][k].  gencb: row-major [g][k].
__global__ void kprep(const float* __restrict__ W1, const float* __restrict__ Wj,
                      const float* __restrict__ W2, const float* __restrict__ W3,
                      const float* __restrict__ ge,
                      short* __restrict__ wcatS, short* __restrict__ w2tS,
                      short* __restrict__ w3t, short* __restrict__ gencb) {
  const int SW1 = 2048 * 512, SWj = 2048 * 128, SPAD = 2048 * 128;
  const int SW2 = 512 * 512, SW3 = 128 * 512, SGE = 512 * 128;
  int t = blockIdx.x * 256 + threadIdx.x;
  if (t < SW1) {
    int n = t & 511, k = t >> 9;
    wcatS[(((size_t)(k >> 3)) * NPAD + n) * 8 + (k & 7)] = f2bf(W1[(size_t)k * 512 + n]);
    return;
  }
  t -= SW1;
  if (t < SWj) {
    int n = t & 127, k = t >> 7;
    wcatS[(((size_t)(k >> 3)) * NPAD + 512 + n) * 8 + (k & 7)] = f2bf(Wj[(size_t)k * 128 + n]);
    return;
  }
  t -= SWj;
  if (t < SPAD) {
    int n = t & 127, k = t >> 7;
    wcatS[(((size_t)(k >> 3)) * NPAD + 640 + n) * 8 + (k & 7)] = 0;
    return;
  }
  t -= SPAD;
  if (t < SW2) {
    int n = t & 511, k = t >> 9;
    w2tS[(((size_t)(k >> 3)) * 512 + n) * 8 + (k & 7)] = f2bf(W2[(size_t)k * 512 + n]);
    return;
  }
  t -= SW2;
  if (t < SW3) {
    int n = t & 127, k = t >> 7;
    w3t[(size_t)n * 512 + k] = f2bf(W3[(size_t)k * 128 + n]);
    return;
  }
  t -= SW3;
  if (t < SGE) gencb[t] = f2bf(ge[t]);
}

// ---- K1: 256x256, BK=64, 512 thr / 8 waves (2Mx4N, wave 128x64), m201-style
// 4-phase/K-tile interleave. Phase = {ds_read quadrant || stage-issue ->
// s_barrier -> lgkmcnt(0) -> setprio(1) 16xMFMA setprio(0) -> s_barrier}.
// Counted vmcnt gates: P2 vmcnt(6) (drains P0's Bh0+Ah0), P3 vmcnt(0)
// (drains P1's Bh1+Ah1, issued >=2 phases earlier). B-frags persist in regs
// across the two m-half phases (LDS reads stay 24/K-tile).
// Grid: bid = r*24 + nt*8 + x, stripe s = r*8+x -> 3 nt-siblings on same XCD.
__global__ __launch_bounds__(512, 2) void k1(
    const float* __restrict__ feat, const short* __restrict__ wcatS,
    const float* __restrict__ b1, const float* __restrict__ b3,
    const float* __restrict__ bj,
    short* __restrict__ h1, short* __restrict__ jmp) {
  __shared__ __align__(16) char L[131072];  // A dbuf 2x32KB @0 (oct-swizzled), B dbuf 2x32KB @65536 (linear)
  const int tid = threadIdx.x;
  const int lane = tid & 63, w = tid >> 6;
  const int l16 = lane & 15, lh = lane >> 4;
  const int mw = w >> 2, nw = w & 3;
  const int bid = blockIdx.x;
  const int r = bid / 24, w24 = bid - r * 24, nt = w24 >> 3, x = w24 & 7;
  const int s = r * 8 + x;
  if (s >= NS256) return;
  const int m0 = s * 256, n0 = nt * 256;

  f32x4 acc[8][4];
#pragma unroll
  for (int m = 0; m < 8; m++)
#pragma unroll
    for (int j = 0; j < 4; j++) acc[m][j] = (f32x4){0.f, 0.f, 0.f, 0.f};

  // A staging: thread covers rows arow0 + j*64 (j=0..3), oct aoct
  const int aoct = tid & 7, arow0 = tid >> 3;
  const int aoctw = aoct ^ (arow0 & 7);
  const float* asrc[4];
  int awr[4];
#pragma unroll
  for (int j = 0; j < 4; j++) {
    int rowg = m0 + arow0 + j * 64;
    if (rowg >= N_NODES) rowg = N_NODES - 1;  // clamp; masked via gid=-1 in k3
    asrc[j] = feat + (size_t)rowg * IN_DIM + aoct * 8;
    awr[j] = (arow0 + j * 64) * 128 + aoctw * 16;
  }
  // B staging: u = i*512+tid; half0 = i 0,1 (octs 0-3), half1 = i 2,3
  const short* bsrc[4];
  int bdst[4];
#pragma unroll
  for (int i = 0; i < 4; i++) {
    int u = i * 512 + tid;
    int oct = u >> 8, nloc = u & 255;
    bsrc[i] = wcatS + ((size_t)oct * NPAD + n0 + nloc) * 8;
    bdst[i] = u * 16;
  }
  const size_t bks = (size_t)8 * NPAD * 8;  // shorts per K-tile in wcatS

  const int aoff0 = (mw * 128 + l16) * 128 + ((0 * 4 + lh) ^ (l16 & 7)) * 16;
  const int aoff1 = (mw * 128 + l16) * 128 + ((1 * 4 + lh) ^ (l16 & 7)) * 16;
  const int boff0 = ((0 * 4 + lh) * 256 + nw * 64 + l16) * 16;
  const int boff1 = ((1 * 4 + lh) * 256 + nw * 64 + l16) * 16;

  f32x4 lo[4], hi[4];

  // ---- prologue: tile 0 -> buf 0
#pragma unroll
  for (int i = 0; i < 4; i++) gload_lds16(bsrc[i], L + 65536 + bdst[i]);
#pragma unroll
  for (int j = 0; j < 4; j++) {
    lo[j] = *(const f32x4*)(asrc[j]);
    hi[j] = *(const f32x4*)(asrc[j] + 4);
  }
  asm volatile("s_waitcnt vmcnt(0)" ::: "memory");
#pragma unroll
  for (int j = 0; j < 4; j++) {
    bf16x8 v;
#pragma unroll
    for (int q = 0; q < 4; q++) { v[q] = f2bf_hw(lo[j][q]); v[q + 4] = f2bf_hw(hi[j][q]); }
    *(bf16x8*)(L + awr[j]) = v;
  }
  asm volatile("s_waitcnt lgkmcnt(0)" ::: "memory");
  __builtin_amdgcn_s_barrier();

#define BARA  do { __builtin_amdgcn_s_barrier(); \
                   asm volatile("s_waitcnt lgkmcnt(0)" ::: "memory"); \
                   __builtin_amdgcn_sched_barrier(0); } while (0)
#define BARB  __builtin_amdgcn_s_barrier()

  for (int kt = 0; kt < 32; ++kt) {
    const int c = kt & 1, nc2 = c ^ 1;
    char* Ac = L + c * 32768;
    char* An = L + nc2 * 32768;
    char* Bc = L + 65536 + c * 32768;
    char* Bn = L + 65536 + nc2 * 32768;
    const bool st = (kt < 31);
    bf16x8 bb[4], a[4];

    // -------- P0: quad (m0-3, ks0); stage Bh0 + Ah0-loads --------
#pragma unroll
    for (int j = 0; j < 4; j++) bb[j] = *(const bf16x8*)(Bc + boff0 + j * 256);
#pragma unroll
    for (int m = 0; m < 4; m++) a[m] = *(const bf16x8*)(Ac + aoff0 + m * 2048);
    if (st) {
      gload_lds16(bsrc[0] + (size_t)(kt + 1) * bks, Bn + bdst[0]);
      gload_lds16(bsrc[1] + (size_t)(kt + 1) * bks, Bn + bdst[1]);
      lo[0] = *(const f32x4*)(asrc[0] + (kt + 1) * 64);
      hi[0] = *(const f32x4*)(asrc[0] + (kt + 1) * 64 + 4);
      lo[1] = *(const f32x4*)(asrc[1] + (kt + 1) * 64);
      hi[1] = *(const f32x4*)(asrc[1] + (kt + 1) * 64 + 4);
    }
    BARA;
    __builtin_amdgcn_s_setprio(1);
#pragma unroll
    for (int m = 0; m < 4; m++)
#pragma unroll
      for (int j = 0; j < 4; j++) acc[m][j] = mfma16(a[m], bb[j], acc[m][j]);
    __builtin_amdgcn_s_setprio(0);
    BARB;

    // -------- P1: quad (m4-7, ks0); stage Bh1 + Ah1-loads --------
#pragma unroll
    for (int m = 0; m < 4; m++) a[m] = *(const bf16x8*)(Ac + aoff0 + (m + 4) * 2048);
    if (st) {
      gload_lds16(bsrc[2] + (size_t)(kt + 1) * bks, Bn + bdst[2]);
      gload_lds16(bsrc[3] + (size_t)(kt + 1) * bks, Bn + bdst[3]);
      lo[2] = *(const f32x4*)(asrc[2] + (kt + 1) * 64);
      hi[2] = *(const f32x4*)(asrc[2] + (kt + 1) * 64 + 4);
      lo[3] = *(const f32x4*)(asrc[3] + (kt + 1) * 64);
      hi[3] = *(const f32x4*)(asrc[3] + (kt + 1) * 64 + 4);
    }
    BARA;
    __builtin_amdgcn_s_setprio(1);
#pragma unroll
    for (int m = 0; m < 4; m++)
#pragma unroll
      for (int j = 0; j < 4; j++) acc[m + 4][j] = mfma16(a[m], bb[j], acc[m + 4][j]);
    __builtin_amdgcn_s_setprio(0);
    BARB;

    // -------- P2: quad (m0-3, ks1); gate Ah0 (vmcnt 6), write A rows j0,j1 --
#pragma unroll
    for (int j = 0; j < 4; j++) bb[j] = *(const bf16x8*)(Bc + boff1 + j * 256);
#pragma unroll
    for (int m = 0; m < 4; m++) a[m] = *(const bf16x8*)(Ac + aoff1 + m * 2048);
    if (st) {
      asm volatile("s_waitcnt vmcnt(6)" ::: "memory");  // P0's Bh0+Ah0 landed
#pragma unroll
      for (int j = 0; j < 2; j++) {
        bf16x8 v;
#pragma unroll
        for (int q = 0; q < 4; q++) { v[q] = f2bf_hw(lo[j][q]); v[q + 4] = f2bf_hw(hi[j][q]); }
        *(bf16x8*)(An + awr[j]) = v;
      }
      asm volatile("s_waitcnt lgkmcnt(0)" ::: "memory");  // writes visible pre-barrier
    }
    BARA;
    __builtin_amdgcn_s_setprio(1);
#pragma unroll
    for (int m = 0; m < 4; m++)
#pragma unroll
      for (int j = 0; j < 4; j++) acc[m][j] = mfma16(a[m], bb[j], acc[m][j]);
    __builtin_amdgcn_s_setprio(0);
    BARB;

    // -------- P3: quad (m4-7, ks1); gate rest (vmcnt 0), write A rows j2,j3 --
#pragma unroll
    for (int m = 0; m < 4; m++) a[m] = *(const bf16x8*)(Ac + aoff1 + (m + 4) * 2048);
    if (st) {
      asm volatile("s_waitcnt vmcnt(0)" ::: "memory");  // Bh1+Ah1 (issued >=2 phases ago)
#pragma unroll
      for (int j = 2; j < 4; j++) {
        bf16x8 v;
#pragma unroll
        for (int q = 0; q < 4; q++) { v[q] = f2bf_hw(lo[j][q]); v[q + 4] = f2bf_hw(hi[j][q]); }
        *(bf16x8*)(An + awr[j]) = v;
      }
      asm volatile("s_waitcnt lgkmcnt(0)" ::: "memory");
    }
    BARA;
    __builtin_amdgcn_s_setprio(1);
#pragma unroll
    for (int m = 0; m < 4; m++)
#pragma unroll
      for (int j = 0; j < 4; j++) acc[m + 4][j] = mfma16(a[m], bb[j], acc[m + 4][j]);
    __builtin_amdgcn_s_setprio(0);
    BARB;
  }
#undef BARA
#undef BARB

  // ---- epilogue (same mapping as the round-14 passing kernel)
#pragma unroll
  for (int j = 0; j < 4; j++) {
    const int col = n0 + nw * 64 + j * 16 + l16;
    if (col < 512) {
      const float bias = b1[col];
#pragma unroll
      for (int m = 0; m < 8; m++) {
        const int row = m0 + mw * 128 + m * 16 + lh * 4;
#pragma unroll
        for (int rr = 0; rr < 4; rr++) {
          float v = acc[m][j][rr] + bias;
          v = v > 0.f ? v : 0.f;
          h1[(size_t)(row + rr) * HID + col] = f2bf(v);
        }
      }
    } else if (col < 640) {
      const int cj = col - 512;
      const float bias = b3[cj] + bj[cj];
#pragma unroll
      for (int m = 0; m < 8; m++) {
        const int row = m0 + mw * 128 + m * 16 + lh * 4;
#pragma unroll
        for (int rr = 0; rr < 4; rr++)
          jmp[(size_t)(row + rr) * OUTD + cj] = f2bf(acc[m][j][rr] + bias);
      }
    }
  }
}

// ---- K2 (round-14 verbatim): 256x256/BK=64; both operands gload_lds dbuf;
// one wait+barrier per K-tile, stages issued post-barrier (drain covers loads
// issued a full compute earlier).
__global__ __launch_bounds__(512, 1) void k2(
    const short* __restrict__ h1, const short* __restrict__ w2tS,
    const float* __restrict__ b2, short* __restrict__ h2) {
  __shared__ __align__(16) char L[131072];
  const int tid = threadIdx.x;
  const int lane = tid & 63, w = tid >> 6;
  const int l16 = lane & 15, lh = lane >> 4;
  const int mw = w >> 2, nw = w & 3;
  const int bid = blockIdx.x;
  const int r = bid >> 4, w16 = bid & 15, nt = w16 >> 3, x = w16 & 7;
  const int s = r * 8 + x;
  if (s >= NS256) return;
  const int m0 = s * 256, n0 = nt * 256;

  f32x4 acc[8][4];
#pragma unroll
  for (int m = 0; m < 8; m++)
#pragma unroll
    for (int j = 0; j < 4; j++) acc[m][j] = (f32x4){0.f, 0.f, 0.f, 0.f};

  const short* asrc[4];
  const short* bsrc[4];
  int adst[4], bdst[4];
#pragma unroll
  for (int i = 0; i < 4; i++) {
    int u = i * 512 + tid;
    int oct = u >> 8, v = u & 255;
    asrc[i] = h1 + (size_t)(m0 + v) * HID + oct * 8;
    bsrc[i] = w2tS + ((size_t)oct * 512 + n0 + v) * 8;
    adst[i] = u * 16;
    bdst[i] = 65536 + u * 16;
  }
  const size_t bkstride = (size_t)8 * 512 * 8;

  int aoffs[2], boffs[2];
#pragma unroll
  for (int ks = 0; ks < 2; ks++) {
    aoffs[ks] = ((ks * 4 + lh) * 256 + mw * 128 + l16) * 16;
    boffs[ks] = 65536 + ((ks * 4 + lh) * 256 + nw * 64 + l16) * 16;
  }

#pragma unroll
  for (int i = 0; i < 4; i++) {
    gload_lds16(asrc[i], L + adst[i]);
    gload_lds16(bsrc[i], L + bdst[i]);
  }

  for (int kt = 0; kt < 8; ++kt) {
    const int c = kt & 1, nc = c ^ 1;
    asm volatile("s_waitcnt vmcnt(0) lgkmcnt(0)" ::: "memory");
    __builtin_amdgcn_s_barrier();
    if (kt < 7) {
#pragma unroll
      for (int i = 0; i < 4; i++) {
        gload_lds16(asrc[i] + (kt + 1) * 64, L + nc * 32768 + adst[i]);
        gload_lds16(bsrc[i] + (size_t)(kt + 1) * bkstride, L + nc * 32768 + bdst[i]);
      }
    }
    __builtin_amdgcn_s_setprio(1);
#pragma unroll
    for (int ks = 0; ks < 2; ks++) {
      bf16x8 b[4];
#pragma unroll
      for (int j = 0; j < 4; j++)
        b[j] = *(const bf16x8*)(L + c * 32768 + boffs[ks] + j * 256);
#pragma unroll
      for (int m = 0; m < 8; m++) {
        bf16x8 a = *(const bf16x8*)(L + c * 32768 + aoffs[ks] + m * 256);
#pragma unroll
        for (int j = 0; j < 4; j++) acc[m][j] = mfma16(a, b[j], acc[m][j]);
      }
    }
    __builtin_amdgcn_s_setprio(0);
  }

#pragma unroll
  for (int j = 0; j < 4; j++) {
    const int col = n0 + nw * 64 + j * 16 + l16;
    const float bias = b2[col];
#pragma unroll
    for (int m = 0; m < 8; m++) {
      const int row = m0 + mw * 128 + m * 16 + lh * 4;
#pragma unroll
      for (int rr = 0; rr < 4; rr++) {
        float v = acc[m][j][rr] + bias;
        v = v > 0.f ? v : 0.f;
        h2[(size_t)(row + rr) * HID + col] = f2bf(v);
      }
    }
  }
}

// ---------------- K3 (round-14 verbatim): l_enc + res-GEMM + JS loss ----------
__global__ __launch_bounds__(256, 2) void k3(
    const short* __restrict__ h2, const short* __restrict__ w3t,
    const short* __restrict__ jmp, const short* __restrict__ genc,
    const int* __restrict__ gid, float* __restrict__ partials) {
  __shared__ __align__(16) short As[128 * 32];
  __shared__ __align__(16) short Bs[128 * 32];
  __shared__ __align__(16) short Ll[128 * 128];
  __shared__ int gids[128];
  __shared__ float sred[8];
  const int mt = blockIdx.x;
  const int m0 = mt * 128;
  const int tid = threadIdx.x;
  const int lane = tid & 63, wid = tid >> 6;
  const int wr = wid >> 1, wc = wid & 1;
  const int l16 = lane & 15, lh = lane >> 4;

  if (tid < 128) {
    int r = m0 + tid;
    gids[tid] = (r < N_NODES) ? gid[r] : -1;
  }

  f32x4 acc[4][4];
#pragma unroll
  for (int i = 0; i < 4; i++)
#pragma unroll
    for (int j = 0; j < 4; j++) acc[i][j] = (f32x4){0.f, 0.f, 0.f, 0.f};

  const short* ap0 = h2 + (size_t)(m0 + (tid >> 2)) * HID + (tid & 3) * 8;
  const short* ap1 = ap0 + (size_t)64 * HID;
  const short* bp0 = w3t + (size_t)(tid >> 2) * HID + (tid & 3) * 8;
  const short* bp1 = bp0 + (size_t)64 * HID;

  for (int kt = 0; kt < HID / 32; ++kt) {
    __syncthreads();
    gload_lds16(ap0 + kt * 32, &As[tid * 8]);
    gload_lds16(ap1 + kt * 32, &As[tid * 8 + 2048]);
    gload_lds16(bp0 + kt * 32, &Bs[tid * 8]);
    gload_lds16(bp1 + kt * 32, &Bs[tid * 8 + 2048]);
    __syncthreads();
    bf16x8 a[4], b[4];
#pragma unroll
    for (int i = 0; i < 4; i++)
      a[i] = *(const bf16x8*)(&As[(wr * 64 + i * 16 + l16) * 32 + lh * 8]);
#pragma unroll
    for (int j = 0; j < 4; j++)
      b[j] = *(const bf16x8*)(&Bs[(wc * 64 + j * 16 + l16) * 32 + lh * 8]);
#pragma unroll
    for (int i = 0; i < 4; i++)
#pragma unroll
      for (int j = 0; j < 4; j++) acc[i][j] = mfma16(a[i], b[j], acc[i][j]);
  }

#pragma unroll
  for (int j = 0; j < 4; j++) {
    const int col = wc * 64 + j * 16 + l16;
#pragma unroll
    for (int i = 0; i < 4; i++) {
      const int rowb = wr * 64 + i * 16 + lh * 4;
#pragma unroll
      for (int r = 0; r < 4; r++) {
        const int row = rowb + r;
        float v = acc[i][j][r] + bf2f(jmp[(size_t)(m0 + row) * OUTD + col]);
        unsigned byte = (unsigned)row * 256u +
                        (((unsigned)col * 2u) ^ (((unsigned)(row & 7)) << 4));
        *(short*)((char*)Ll + byte) = f2bf(v);
      }
    }
  }
  __syncthreads();

  int myg[4][4];
#pragma unroll
  for (int i = 0; i < 4; i++)
#pragma unroll
    for (int r = 0; r < 4; r++) myg[i][r] = gids[wr * 64 + i * 16 + lh * 4 + r];

  float pacc = 0.f, nacc = 0.f;
  for (int nc = 0; nc < 4; ++nc) {
    f32x4 a2[4][4];
#pragma unroll
    for (int i = 0; i < 4; i++)
#pragma unroll
      for (int j = 0; j < 4; j++) a2[i][j] = (f32x4){0.f, 0.f, 0.f, 0.f};
#pragma unroll
    for (int ks = 0; ks < 4; ++ks) {
      bf16x8 af[4], bg[4];
#pragma unroll
      for (int i = 0; i < 4; i++) {
        const int row = wr * 64 + i * 16 + l16;
        unsigned byte = (unsigned)row * 256u +
                        (((unsigned)(ks * 64 + lh * 16)) ^ (((unsigned)(row & 7)) << 4));
        af[i] = *(const bf16x8*)((const char*)Ll + byte);
      }
#pragma unroll
      for (int j = 0; j < 4; j++) {
        const int g = nc * 128 + wc * 64 + j * 16 + l16;
        bg[j] = *(const bf16x8*)(genc + (size_t)g * OUTD + ks * 32 + lh * 8);
      }
#pragma unroll
      for (int i = 0; i < 4; i++)
#pragma unroll
        for (int j = 0; j < 4; j++) a2[i][j] = mfma16(af[i], bg[j], a2[i][j]);
    }
#pragma unroll
    for (int j = 0; j < 4; j++) {
      const int g = nc * 128 + wc * 64 + j * 16 + l16;
#pragma unroll
      for (int i = 0; i < 4; i++) {
#pragma unroll
        for (int r = 0; r < 4; r++) {
          float rv = a2[i][j][r];
          int gr = myg[i][r];
          float t = __expf(-fabsf(rv));
          float lg = __logf(1.f + t);
          if (gr == g)
            pacc += LOG2F_ - (fmaxf(-rv, 0.f) + lg);
          else if (gr >= 0)
            nacc += (fmaxf(rv, 0.f) + lg) - LOG2F_;
        }
      }
    }
  }

#pragma unroll
  for (int o = 32; o; o >>= 1) {
    pacc += __shfl_down(pacc, o);
    nacc += __shfl_down(nacc, o);
  }
  if (lane == 0) { sred[wid] = pacc; sred[4 + wid] = nacc; }
  __syncthreads();
  if (tid == 0) {
    partials[2 * mt] = sred[0] + sred[1] + sred[2] + sred[3];
    partials[2 * mt + 1] = sred[4] + sred[5] + sred[6] + sred[7];
  }
}

// ---------------- K4: deterministic final reduction ---------------------------
__global__ void k4(const float* __restrict__ partials, float* __restrict__ out) {
  const int tid = threadIdx.x;
  float p = 0.f, n = 0.f;
  for (int i = tid; i < MT; i += 256) {
    p += partials[2 * i];
    n += partials[2 * i + 1];
  }
#pragma unroll
  for (int o = 32; o; o >>= 1) {
    p += __shfl_down(p, o);
    n += __shfl_down(n, o);
  }
  __shared__ float sp[4], sn[4];
  const int wid = tid >> 6, lane = tid & 63;
  if (lane == 0) { sp[wid] = p; sn[wid] = n; }
  __syncthreads();
  if (tid == 0) {
    float P = sp[0] + sp[1] + sp[2] + sp[3];
    float Nn = sn[0] + sn[1] + sn[2] + sn[3];
    out[0] = Nn / (100000.0f * 511.0f) - P / 100000.0f;
  }
}

extern "C" void kernel_launch(void* const* d_in, const int* in_sizes, int n_in,
                              void* d_out, int out_size, void* d_ws, size_t ws_size,
                              hipStream_t stream) {
  const float* feat = (const float*)d_in[0];
  const float* genc_f = (const float*)d_in[1];
  const int* gid = (const int*)d_in[2];
  const float* W1 = (const float*)d_in[3];
  const float* b1 = (const float*)d_in[4];
  const float* W2 = (const float*)d_in[5];
  const float* b2 = (const float*)d_in[6];
  const float* W3 = (const float*)d_in[7];
  const float* b3 = (const float*)d_in[8];
  const float* Wj = (const float*)d_in[9];
  const float* bj = (const float*)d_in[10];
  float* out = (float*)d_out;

  char* ws = (char*)d_ws;
  float* partials = (float*)ws;                       // 782*2 f32
  short* wcatS = (short*)(ws + 8192);                 // [256][768][8] k-slot
  short* w2tS = wcatS + (size_t)256 * NPAD * 8;       // [64][512][8] k-slot
  short* w3t = w2tS + (size_t)64 * 512 * 8;           // [128][512] row-major
  short* gencb = w3t + (size_t)128 * 512;             // [512][128] row-major
  short* h1 = gencb + (size_t)512 * 128;              // [MPAD][512]
  short* h2 = h1 + (size_t)MPAD * 512;                // [MPAD][512]
  short* jmp = h2 + (size_t)MPAD * 512;               // [MPAD][128]

  kprep<<<7680, 256, 0, stream>>>(W1, Wj, W2, W3, genc_f, wcatS, w2tS, w3t, gencb);
  k1<<<49 * 24, 512, 0, stream>>>(feat, wcatS, b1, b3, bj, h1, jmp);
  k2<<<49 * 16, 512, 0, stream>>>(h1, w2tS, b2, h2);
  k3<<<MT, 256, 0, stream>>>(h2, w3t, jmp, gencb, gid, partials);
  k4<<<1, 256, 0, stream>>>(partials, out);
}

// Round 17
// 647.834 us; speedup vs baseline: 1.1597x; 1.1597x over previous
//
#include <hip/hip_runtime.h>
#include <hip/hip_bf16.h>
#include <stdint.h>

#define N_NODES 100000
#define MT      782          // 128-row tiles (k3)
#define NS256   391          // 256-row stripes (k1,k2)
#define MPAD    (MT*128)     // 100096 = 391*256
#define IN_DIM  2048
#define HID     512
#define OUTD    128
#define NG      512
#define NPAD    768          // k1 padded N (3 x 256)
#define LOG2F_  0.69314718055994531f

typedef __attribute__((ext_vector_type(4))) float f32x4;
typedef __attribute__((ext_vector_type(8))) short bf16x8;

typedef const __attribute__((address_space(1))) unsigned int gas_u32;
typedef __attribute__((address_space(3))) unsigned int las_u32;

__device__ __forceinline__ void gload_lds16(const void* g, void* lds) {
  __builtin_amdgcn_global_load_lds((gas_u32*)g, (las_u32*)lds, 16, 0, 0);
}

__device__ __forceinline__ short f2bf(float f) {   // manual RNE
  unsigned u = __builtin_bit_cast(unsigned, f);
  u = (u + 0x7fffu + ((u >> 16) & 1u)) >> 16;
  return (short)u;
}
__device__ __forceinline__ short f2bf_hw(float f) {
  __hip_bfloat16 h = __float2bfloat16(f);
  return __builtin_bit_cast(short, h);
}
__device__ __forceinline__ float bf2f(short s) {
  unsigned u = ((unsigned)(unsigned short)s) << 16;
  return __builtin_bit_cast(float, u);
}

__device__ __forceinline__ f32x4 mfma16(bf16x8 a, bf16x8 b, f32x4 c) {
  return __builtin_amdgcn_mfma_f32_16x16x32_bf16(a, b, c, 0, 0, 0);
}

// ---------------- prep (coalesced: consecutive threads -> consecutive n) ------
// wcatS: k-slot [k/8][NPAD][e] ([W1|Wj] cols 0..639, zero-pad 640..767).
// w2tS : k-slot [k/8][512][e].  w3t: row-major [n][k].  gencb: row-major [g][k].
__global__ void kprep(const float* __restrict__ W1, const float* __restrict__ Wj,
                      const float* __restrict__ W2, const float* __restrict__ W3,
                      const float* __restrict__ ge,
                      short* __restrict__ wcatS, short* __restrict__ w2tS,
                      short* __restrict__ w3t, short* __restrict__ gencb) {
  const int SW1 = 2048 * 512, SWj = 2048 * 128, SPAD = 2048 * 128;
  const int SW2 = 512 * 512, SW3 = 128 * 512, SGE = 512 * 128;
  int t = blockIdx.x * 256 + threadIdx.x;
  if (t < SW1) {
    int n = t & 511, k = t >> 9;
    wcatS[(((size_t)(k >> 3)) * NPAD + n) * 8 + (k & 7)] = f2bf(W1[(size_t)k * 512 + n]);
    return;
  }
  t -= SW1;
  if (t < SWj) {
    int n = t & 127, k = t >> 7;
    wcatS[(((size_t)(k >> 3)) * NPAD + 512 + n) * 8 + (k & 7)] = f2bf(Wj[(size_t)k * 128 + n]);
    return;
  }
  t -= SWj;
  if (t < SPAD) {
    int n = t & 127, k = t >> 7;
    wcatS[(((size_t)(k >> 3)) * NPAD + 640 + n) * 8 + (k & 7)] = 0;
    return;
  }
  t -= SPAD;
  if (t < SW2) {
    int n = t & 511, k = t >> 9;
    w2tS[(((size_t)(k >> 3)) * 512 + n) * 8 + (k & 7)] = f2bf(W2[(size_t)k * 512 + n]);
    return;
  }
  t -= SW2;
  if (t < SW3) {
    int n = t & 127, k = t >> 7;
    w3t[(size_t)n * 512 + k] = f2bf(W3[(size_t)k * 128 + n]);
    return;
  }
  t -= SW3;
  if (t < SGE) gencb[t] = f2bf(ge[t]);
}

// ---- K1 (round-14 best): 256x256, BK=64, 512 thr / 8 waves (2Mx4N, wave
// 128x64). Single barrier + single vmcnt(0) per K-tile, placed AFTER the
// 64-MFMA cluster so staging latency is covered by ~2500 cyc of compute.
// A (f32) reg-staged (issued pre-compute), cvt + XOR-swizzled ds_write after
// compute. B via gload_lds from k-slot wcatS (linear dest, coalesced src).
// Grid: bid = r*24 + nt*8 + x, stripe s = r*8+x -> 3 nt-siblings on same XCD.
__global__ __launch_bounds__(512, 1) void k1(
    const float* __restrict__ feat, const short* __restrict__ wcatS,
    const float* __restrict__ b1, const float* __restrict__ b3,
    const float* __restrict__ bj,
    short* __restrict__ h1, short* __restrict__ jmp) {
  __shared__ __align__(16) char L[131072];  // A dbuf 2x32KB @0 (oct-swz), B dbuf 2x32KB @65536 (linear)
  const int tid = threadIdx.x;
  const int lane = tid & 63, w = tid >> 6;
  const int l16 = lane & 15, lh = lane >> 4;
  const int mw = w >> 2, nw = w & 3;
  const int bid = blockIdx.x;
  const int r = bid / 24, w24 = bid - r * 24, nt = w24 >> 3, x = w24 & 7;
  const int s = r * 8 + x;
  if (s >= NS256) return;
  const int m0 = s * 256;
  const int n0 = nt * 256;

  f32x4 acc[8][4];
#pragma unroll
  for (int m = 0; m < 8; m++)
#pragma unroll
    for (int j = 0; j < 4; j++) acc[m][j] = (f32x4){0.f, 0.f, 0.f, 0.f};

  const int aoct = tid & 7;
  const int arow0 = tid >> 3;
  const int aoctw = aoct ^ (arow0 & 7);
  const float* asrc[4];
#pragma unroll
  for (int j = 0; j < 4; j++) {
    int rowg = m0 + arow0 + j * 64;
    if (rowg >= N_NODES) rowg = N_NODES - 1;  // clamp; masked via gid=-1 in k3
    asrc[j] = feat + (size_t)rowg * IN_DIM + aoct * 8;
  }
  int awr[4];
#pragma unroll
  for (int j = 0; j < 4; j++) awr[j] = (arow0 + j * 64) * 128 + aoctw * 16;

  const short* bsrc[4];
  int bdst[4];
#pragma unroll
  for (int i = 0; i < 4; i++) {
    int u = i * 512 + tid;
    int oct = u >> 8, nloc = u & 255;
    bsrc[i] = wcatS + ((size_t)oct * NPAD + n0 + nloc) * 8;
    bdst[i] = 65536 + u * 16;
  }
  const size_t bkstride = (size_t)8 * NPAD * 8;

  int aoffs[2], boffs[2];
#pragma unroll
  for (int ks = 0; ks < 2; ks++) {
    aoffs[ks] = (mw * 128 + l16) * 128 + ((ks * 4 + lh) ^ (l16 & 7)) * 16;
    boffs[ks] = 65536 + ((ks * 4 + lh) * 256 + nw * 64 + l16) * 16;
  }

  f32x4 lo[4], hi[4];

  // ---- prologue: stage tile 0 into buffer 0
#pragma unroll
  for (int i = 0; i < 4; i++) gload_lds16(bsrc[i], L + bdst[i]);
#pragma unroll
  for (int j = 0; j < 4; j++) {
    lo[j] = *(const f32x4*)(asrc[j]);
    hi[j] = *(const f32x4*)(asrc[j] + 4);
  }
  asm volatile("s_waitcnt vmcnt(0)" ::: "memory");
#pragma unroll
  for (int j = 0; j < 4; j++) {
    bf16x8 v;
#pragma unroll
    for (int q = 0; q < 4; q++) { v[q] = f2bf_hw(lo[j][q]); v[q + 4] = f2bf_hw(hi[j][q]); }
    *(bf16x8*)(L + awr[j]) = v;
  }
  asm volatile("s_waitcnt lgkmcnt(0)\ns_barrier" ::: "memory");

  for (int kt = 0; kt < 32; ++kt) {
    const int c = kt & 1, nc = c ^ 1;
    // stage issue for tile kt+1 (covered by the compute below)
    if (kt < 31) {
#pragma unroll
      for (int i = 0; i < 4; i++)
        gload_lds16(bsrc[i] + (size_t)(kt + 1) * bkstride, L + nc * 32768 + bdst[i]);
#pragma unroll
      for (int j = 0; j < 4; j++) {
        lo[j] = *(const f32x4*)(asrc[j] + (kt + 1) * 64);
        hi[j] = *(const f32x4*)(asrc[j] + (kt + 1) * 64 + 4);
      }
    }
    // compute from buffer c
    __builtin_amdgcn_s_setprio(1);
#pragma unroll
    for (int ks = 0; ks < 2; ks++) {
      bf16x8 b[4];
#pragma unroll
      for (int j = 0; j < 4; j++)
        b[j] = *(const bf16x8*)(L + c * 32768 + boffs[ks] + j * 256);
#pragma unroll
      for (int m = 0; m < 8; m++) {
        bf16x8 a = *(const bf16x8*)(L + c * 32768 + aoffs[ks] + m * 2048);
#pragma unroll
        for (int j = 0; j < 4; j++) acc[m][j] = mfma16(a, b[j], acc[m][j]);
      }
    }
    __builtin_amdgcn_s_setprio(0);
    if (kt < 31) {
      asm volatile("s_waitcnt vmcnt(0)" ::: "memory");  // A regs + B DMA landed
#pragma unroll
      for (int j = 0; j < 4; j++) {
        bf16x8 v;
#pragma unroll
        for (int q = 0; q < 4; q++) { v[q] = f2bf_hw(lo[j][q]); v[q + 4] = f2bf_hw(hi[j][q]); }
        *(bf16x8*)(L + nc * 32768 + awr[j]) = v;
      }
      asm volatile("s_waitcnt lgkmcnt(0)\ns_barrier" ::: "memory");
    }
  }

  // ---- epilogue
#pragma unroll
  for (int j = 0; j < 4; j++) {
    const int col = n0 + nw * 64 + j * 16 + l16;
    if (col < 512) {
      const float bias = b1[col];
#pragma unroll
      for (int m = 0; m < 8; m++) {
        const int row = m0 + mw * 128 + m * 16 + lh * 4;
#pragma unroll
        for (int rr = 0; rr < 4; rr++) {
          float v = acc[m][j][rr] + bias;
          v = v > 0.f ? v : 0.f;
          h1[(size_t)(row + rr) * HID + col] = f2bf(v);
        }
      }
    } else if (col < 640) {
      const int cj = col - 512;
      const float bias = b3[cj] + bj[cj];
#pragma unroll
      for (int m = 0; m < 8; m++) {
        const int row = m0 + mw * 128 + m * 16 + lh * 4;
#pragma unroll
        for (int rr = 0; rr < 4; rr++)
          jmp[(size_t)(row + rr) * OUTD + cj] = f2bf(acc[m][j][rr] + bias);
      }
    }
  }
}

// ---- K2 (round-14 verbatim): 256x256/BK=64; both operands gload_lds dbuf;
// one wait+barrier per K-tile, stages issued post-barrier.
__global__ __launch_bounds__(512, 1) void k2(
    const short* __restrict__ h1, const short* __restrict__ w2tS,
    const float* __restrict__ b2, short* __restrict__ h2) {
  __shared__ __align__(16) char L[131072];
  const int tid = threadIdx.x;
  const int lane = tid & 63, w = tid >> 6;
  const int l16 = lane & 15, lh = lane >> 4;
  const int mw = w >> 2, nw = w & 3;
  const int bid = blockIdx.x;
  const int r = bid >> 4, w16 = bid & 15, nt = w16 >> 3, x = w16 & 7;
  const int s = r * 8 + x;
  if (s >= NS256) return;
  const int m0 = s * 256, n0 = nt * 256;

  f32x4 acc[8][4];
#pragma unroll
  for (int m = 0; m < 8; m++)
#pragma unroll
    for (int j = 0; j < 4; j++) acc[m][j] = (f32x4){0.f, 0.f, 0.f, 0.f};

  const short* asrc[4];
  const short* bsrc[4];
  int adst[4], bdst[4];
#pragma unroll
  for (int i = 0; i < 4; i++) {
    int u = i * 512 + tid;
    int oct = u >> 8, v = u & 255;
    asrc[i] = h1 + (size_t)(m0 + v) * HID + oct * 8;
    bsrc[i] = w2tS + ((size_t)oct * 512 + n0 + v) * 8;
    adst[i] = u * 16;
    bdst[i] = 65536 + u * 16;
  }
  const size_t bkstride = (size_t)8 * 512 * 8;

  int aoffs[2], boffs[2];
#pragma unroll
  for (int ks = 0; ks < 2; ks++) {
    aoffs[ks] = ((ks * 4 + lh) * 256 + mw * 128 + l16) * 16;
    boffs[ks] = 65536 + ((ks * 4 + lh) * 256 + nw * 64 + l16) * 16;
  }

#pragma unroll
  for (int i = 0; i < 4; i++) {
    gload_lds16(asrc[i], L + adst[i]);
    gload_lds16(bsrc[i], L + bdst[i]);
  }

  for (int kt = 0; kt < 8; ++kt) {
    const int c = kt & 1, nc = c ^ 1;
    asm volatile("s_waitcnt vmcnt(0) lgkmcnt(0)" ::: "memory");
    __builtin_amdgcn_s_barrier();
    if (kt < 7) {
#pragma unroll
      for (int i = 0; i < 4; i++) {
        gload_lds16(asrc[i] + (kt + 1) * 64, L + nc * 32768 + adst[i]);
        gload_lds16(bsrc[i] + (size_t)(kt + 1) * bkstride, L + nc * 32768 + bdst[i]);
      }
    }
    __builtin_amdgcn_s_setprio(1);
#pragma unroll
    for (int ks = 0; ks < 2; ks++) {
      bf16x8 b[4];
#pragma unroll
      for (int j = 0; j < 4; j++)
        b[j] = *(const bf16x8*)(L + c * 32768 + boffs[ks] + j * 256);
#pragma unroll
      for (int m = 0; m < 8; m++) {
        bf16x8 a = *(const bf16x8*)(L + c * 32768 + aoffs[ks] + m * 256);
#pragma unroll
        for (int j = 0; j < 4; j++) acc[m][j] = mfma16(a, b[j], acc[m][j]);
      }
    }
    __builtin_amdgcn_s_setprio(0);
  }

#pragma unroll
  for (int j = 0; j < 4; j++) {
    const int col = n0 + nw * 64 + j * 16 + l16;
    const float bias = b2[col];
#pragma unroll
    for (int m = 0; m < 8; m++) {
      const int row = m0 + mw * 128 + m * 16 + lh * 4;
#pragma unroll
      for (int rr = 0; rr < 4; rr++) {
        float v = acc[m][j][rr] + bias;
        v = v > 0.f ? v : 0.f;
        h2[(size_t)(row + rr) * HID + col] = f2bf(v);
      }
    }
  }
}

// ---------------- K3 (round-14 verbatim): l_enc + res-GEMM + JS loss ----------
__global__ __launch_bounds__(256, 2) void k3(
    const short* __restrict__ h2, const short* __restrict__ w3t,
    const short* __restrict__ jmp, const short* __restrict__ genc,
    const int* __restrict__ gid, float* __restrict__ partials) {
  __shared__ __align__(16) short As[128 * 32];
  __shared__ __align__(16) short Bs[128 * 32];
  __shared__ __align__(16) short Ll[128 * 128];
  __shared__ int gids[128];
  __shared__ float sred[8];
  const int mt = blockIdx.x;
  const int m0 = mt * 128;
  const int tid = threadIdx.x;
  const int lane = tid & 63, wid = tid >> 6;
  const int wr = wid >> 1, wc = wid & 1;
  const int l16 = lane & 15, lh = lane >> 4;

  if (tid < 128) {
    int r = m0 + tid;
    gids[tid] = (r < N_NODES) ? gid[r] : -1;
  }

  f32x4 acc[4][4];
#pragma unroll
  for (int i = 0; i < 4; i++)
#pragma unroll
    for (int j = 0; j < 4; j++) acc[i][j] = (f32x4){0.f, 0.f, 0.f, 0.f};

  const short* ap0 = h2 + (size_t)(m0 + (tid >> 2)) * HID + (tid & 3) * 8;
  const short* ap1 = ap0 + (size_t)64 * HID;
  const short* bp0 = w3t + (size_t)(tid >> 2) * HID + (tid & 3) * 8;
  const short* bp1 = bp0 + (size_t)64 * HID;

  for (int kt = 0; kt < HID / 32; ++kt) {
    __syncthreads();
    gload_lds16(ap0 + kt * 32, &As[tid * 8]);
    gload_lds16(ap1 + kt * 32, &As[tid * 8 + 2048]);
    gload_lds16(bp0 + kt * 32, &Bs[tid * 8]);
    gload_lds16(bp1 + kt * 32, &Bs[tid * 8 + 2048]);
    __syncthreads();
    bf16x8 a[4], b[4];
#pragma unroll
    for (int i = 0; i < 4; i++)
      a[i] = *(const bf16x8*)(&As[(wr * 64 + i * 16 + l16) * 32 + lh * 8]);
#pragma unroll
    for (int j = 0; j < 4; j++)
      b[j] = *(const bf16x8*)(&Bs[(wc * 64 + j * 16 + l16) * 32 + lh * 8]);
#pragma unroll
    for (int i = 0; i < 4; i++)
#pragma unroll
      for (int j = 0; j < 4; j++) acc[i][j] = mfma16(a[i], b[j], acc[i][j]);
  }

#pragma unroll
  for (int j = 0; j < 4; j++) {
    const int col = wc * 64 + j * 16 + l16;
#pragma unroll
    for (int i = 0; i < 4; i++) {
      const int rowb = wr * 64 + i * 16 + lh * 4;
#pragma unroll
      for (int r = 0; r < 4; r++) {
        const int row = rowb + r;
        float v = acc[i][j][r] + bf2f(jmp[(size_t)(m0 + row) * OUTD + col]);
        unsigned byte = (unsigned)row * 256u +
                        (((unsigned)col * 2u) ^ (((unsigned)(row & 7)) << 4));
        *(short*)((char*)Ll + byte) = f2bf(v);
      }
    }
  }
  __syncthreads();

  int myg[4][4];
#pragma unroll
  for (int i = 0; i < 4; i++)
#pragma unroll
    for (int r = 0; r < 4; r++) myg[i][r] = gids[wr * 64 + i * 16 + lh * 4 + r];

  float pacc = 0.f, nacc = 0.f;
  for (int nc = 0; nc < 4; ++nc) {
    f32x4 a2[4][4];
#pragma unroll
    for (int i = 0; i < 4; i++)
#pragma unroll
      for (int j = 0; j < 4; j++) a2[i][j] = (f32x4){0.f, 0.f, 0.f, 0.f};
#pragma unroll
    for (int ks = 0; ks < 4; ++ks) {
      bf16x8 af[4], bg[4];
#pragma unroll
      for (int i = 0; i < 4; i++) {
        const int row = wr * 64 + i * 16 + l16;
        unsigned byte = (unsigned)row * 256u +
                        (((unsigned)(ks * 64 + lh * 16)) ^ (((unsigned)(row & 7)) << 4));
        af[i] = *(const bf16x8*)((const char*)Ll + byte);
      }
#pragma unroll
      for (int j = 0; j < 4; j++) {
        const int g = nc * 128 + wc * 64 + j * 16 + l16;
        bg[j] = *(const bf16x8*)(genc + (size_t)g * OUTD + ks * 32 + lh * 8);
      }
#pragma unroll
      for (int i = 0; i < 4; i++)
#pragma unroll
        for (int j = 0; j < 4; j++) a2[i][j] = mfma16(af[i], bg[j], a2[i][j]);
    }
#pragma unroll
    for (int j = 0; j < 4; j++) {
      const int g = nc * 128 + wc * 64 + j * 16 + l16;
#pragma unroll
      for (int i = 0; i < 4; i++) {
#pragma unroll
        for (int r = 0; r < 4; r++) {
          float rv = a2[i][j][r];
          int gr = myg[i][r];
          float t = __expf(-fabsf(rv));
          float lg = __logf(1.f + t);
          if (gr == g)
            pacc += LOG2F_ - (fmaxf(-rv, 0.f) + lg);
          else if (gr >= 0)
            nacc += (fmaxf(rv, 0.f) + lg) - LOG2F_;
        }
      }
    }
  }

#pragma unroll
  for (int o = 32; o; o >>= 1) {
    pacc += __shfl_down(pacc, o);
    nacc += __shfl_down(nacc, o);
  }
  if (lane == 0) { sred[wid] = pacc; sred[4 + wid] = nacc; }
  __syncthreads();
  if (tid == 0) {
    partials[2 * mt] = sred[0] + sred[1] + sred[2] + sred[3];
    partials[2 * mt + 1] = sred[4] + sred[5] + sred[6] + sred[7];
  }
}

// ---------------- K4: deterministic final reduction ---------------------------
__global__ void k4(const float* __restrict__ partials, float* __restrict__ out) {
  const int tid = threadIdx.x;
  float p = 0.f, n = 0.f;
  for (int i = tid; i < MT; i += 256) {
    p += partials[2 * i];
    n += partials[2 * i + 1];
  }
#pragma unroll
  for (int o = 32; o; o >>= 1) {
    p += __shfl_down(p, o);
    n += __shfl_down(n, o);
  }
  __shared__ float sp[4], sn[4];
  const int wid = tid >> 6, lane = tid & 63;
  if (lane == 0) { sp[wid] = p; sn[wid] = n; }
  __syncthreads();
  if (tid == 0) {
    float P = sp[0] + sp[1] + sp[2] + sp[3];
    float Nn = sn[0] + sn[1] + sn[2] + sn[3];
    out[0] = Nn / (100000.0f * 511.0f) - P / 100000.0f;
  }
}

extern "C" void kernel_launch(void* const* d_in, const int* in_sizes, int n_in,
                              void* d_out, int out_size, void* d_ws, size_t ws_size,
                              hipStream_t stream) {
  const float* feat = (const float*)d_in[0];
  const float* genc_f = (const float*)d_in[1];
  const int* gid = (const int*)d_in[2];
  const float* W1 = (const float*)d_in[3];
  const float* b1 = (const float*)d_in[4];
  const float* W2 = (const float*)d_in[5];
  const float* b2 = (const float*)d_in[6];
  const float* W3 = (const float*)d_in[7];
  const float* b3 = (const float*)d_in[8];
  const float* Wj = (const float*)d_in[9];
  const float* bj = (const float*)d_in[10];
  float* out = (float*)d_out;

  char* ws = (char*)d_ws;
  float* partials = (float*)ws;                       // 782*2 f32
  short* wcatS = (short*)(ws + 8192);                 // [256][768][8] k-slot
  short* w2tS = wcatS + (size_t)256 * NPAD * 8;       // [64][512][8] k-slot
  short* w3t = w2tS + (size_t)64 * 512 * 8;           // [128][512] row-major
  short* gencb = w3t + (size_t)128 * 512;             // [512][128] row-major
  short* h1 = gencb + (size_t)512 * 128;              // [MPAD][512]
  short* h2 = h1 + (size_t)MPAD * 512;                // [MPAD][512]
  short* jmp = h2 + (size_t)MPAD * 512;               // [MPAD][128]

  kprep<<<7680, 256, 0, stream>>>(W1, Wj, W2, W3, genc_f, wcatS, w2tS, w3t, gencb);
  k1<<<49 * 24, 512, 0, stream>>>(feat, wcatS, b1, b3, bj, h1, jmp);
  k2<<<49 * 16, 512, 0, stream>>>(h1, w2tS, b2, h2);
  k3<<<MT, 256, 0, stream>>>(h2, w3t, jmp, gencb, gid, partials);
  k4<<<1, 256, 0, stream>>>(partials, out);
}

// Round 18
// 619.664 us; speedup vs baseline: 1.2124x; 1.0455x over previous
//
#include <hip/hip_runtime.h>
#include <hip/hip_bf16.h>
#include <stdint.h>

#define N_NODES 100000
#define MT      782          // 128-row tiles (k3)
#define NS256   391          // 256-row stripes (k1,k2)
#define MPAD    (MT*128)     // 100096 = 391*256
#define IN_DIM  2048
#define HID     512
#define OUTD    128
#define NG      512
#define NW1     640          // k1 B width (512 + 128, no pad)
#define LOG2F_  0.69314718055994531f

typedef __attribute__((ext_vector_type(4))) float f32x4;
typedef __attribute__((ext_vector_type(8))) short bf16x8;

typedef const __attribute__((address_space(1))) unsigned int gas_u32;
typedef __attribute__((address_space(3))) unsigned int las_u32;

__device__ __forceinline__ void gload_lds16(const void* g, void* lds) {
  __builtin_amdgcn_global_load_lds((gas_u32*)g, (las_u32*)lds, 16, 0, 0);
}

__device__ __forceinline__ short f2bf(float f) {   // manual RNE
  unsigned u = __builtin_bit_cast(unsigned, f);
  u = (u + 0x7fffu + ((u >> 16) & 1u)) >> 16;
  return (short)u;
}
__device__ __forceinline__ short f2bf_hw(float f) {
  __hip_bfloat16 h = __float2bfloat16(f);
  return __builtin_bit_cast(short, h);
}
__device__ __forceinline__ float bf2f(short s) {
  unsigned u = ((unsigned)(unsigned short)s) << 16;
  return __builtin_bit_cast(float, u);
}

__device__ __forceinline__ f32x4 mfma16(bf16x8 a, bf16x8 b, f32x4 c) {
  return __builtin_amdgcn_mfma_f32_16x16x32_bf16(a, b, c, 0, 0, 0);
}

// ---------------- prep (coalesced: consecutive threads -> consecutive n) ------
// wcatS: k-slot [k/8][640][e] ([W1 | Wj], no padding).
// w2tS : k-slot [k/8][512][e].  w3t: row-major [n][k].  gencb: row-major [g][k].
__global__ void kprep(const float* __restrict__ W1, const float* __restrict__ Wj,
                      const float* __restrict__ W2, const float* __restrict__ W3,
                      const float* __restrict__ ge,
                      short* __restrict__ wcatS, short* __restrict__ w2tS,
                      short* __restrict__ w3t, short* __restrict__ gencb) {
  const int SW1 = 2048 * 512, SWj = 2048 * 128;
  const int SW2 = 512 * 512, SW3 = 128 * 512, SGE = 512 * 128;
  int t = blockIdx.x * 256 + threadIdx.x;
  if (t < SW1) {
    int n = t & 511, k = t >> 9;
    wcatS[(((size_t)(k >> 3)) * NW1 + n) * 8 + (k & 7)] = f2bf(W1[(size_t)k * 512 + n]);
    return;
  }
  t -= SW1;
  if (t < SWj) {
    int n = t & 127, k = t >> 7;
    wcatS[(((size_t)(k >> 3)) * NW1 + 512 + n) * 8 + (k & 7)] = f2bf(Wj[(size_t)k * 128 + n]);
    return;
  }
  t -= SWj;
  if (t < SW2) {
    int n = t & 511, k = t >> 9;
    w2tS[(((size_t)(k >> 3)) * 512 + n) * 8 + (k & 7)] = f2bf(W2[(size_t)k * 512 + n]);
    return;
  }
  t -= SW2;
  if (t < SW3) {
    int n = t & 127, k = t >> 7;
    w3t[(size_t)n * 512 + k] = f2bf(W3[(size_t)k * 128 + n]);
    return;
  }
  t -= SW3;
  if (t < SGE) gencb[t] = f2bf(ge[t]);
}

// ---- K1: dual-geometry, no padded columns.
// nt<2 : 256x256 tile (R14-proven), wave 128x64 (2Mx4N), acc 8x4, cols nt*256.
// nt==2: 256x128 tile, wave 64x64 (4Mx2N), acc 4x4, cols 512..639 -> jump.
// Both: BK=64, single barrier + single vmcnt(0) per K-tile AFTER the MFMA
// cluster; A (f32) reg-staged -> cvt -> XOR-swizzled ds_write; B via gload_lds
// from k-slot wcatS (linear dest, coalesced src).
// Grid: bid = r*24 + nt*8 + x, stripe s = r*8+x -> 3 nt-siblings on same XCD.
__global__ __launch_bounds__(512, 1) void k1(
    const float* __restrict__ feat, const short* __restrict__ wcatS,
    const float* __restrict__ b1, const float* __restrict__ b3,
    const float* __restrict__ bj,
    short* __restrict__ h1, short* __restrict__ jmp) {
  __shared__ __align__(16) char L[131072];  // A dbuf 2x32KB @0 (oct-swz), B dbuf 2x32KB @65536 (linear)
  const int tid = threadIdx.x;
  const int lane = tid & 63, w = tid >> 6;
  const int l16 = lane & 15, lh = lane >> 4;
  const int bid = blockIdx.x;
  const int r = bid / 24, w24 = bid - r * 24, nt = w24 >> 3, x = w24 & 7;
  const int s = r * 8 + x;
  if (s >= NS256) return;
  const int m0 = s * 256;

  // ---- A staging geometry (shared by both paths)
  const int aoct = tid & 7;
  const int arow0 = tid >> 3;
  const int aoctw = aoct ^ (arow0 & 7);
  const float* asrc[4];
  int awr[4];
#pragma unroll
  for (int j = 0; j < 4; j++) {
    int rowg = m0 + arow0 + j * 64;
    if (rowg >= N_NODES) rowg = N_NODES - 1;  // clamp; masked via gid=-1 in k3
    asrc[j] = feat + (size_t)rowg * IN_DIM + aoct * 8;
    awr[j] = (arow0 + j * 64) * 128 + aoctw * 16;
  }
  const size_t bks = (size_t)8 * NW1 * 8;  // shorts per K-tile in wcatS
  f32x4 lo[4], hi[4];

  if (nt < 2) {
    // ================= path A: 256x256, wave 128x64, acc 8x4 =================
    const int mw = w >> 2, nw = w & 3;
    const int n0 = nt * 256;

    f32x4 acc[8][4];
#pragma unroll
    for (int m = 0; m < 8; m++)
#pragma unroll
      for (int j = 0; j < 4; j++) acc[m][j] = (f32x4){0.f, 0.f, 0.f, 0.f};

    const short* bsrc[4];
    int bdst[4];
#pragma unroll
    for (int i = 0; i < 4; i++) {
      int u = i * 512 + tid;
      int oct = u >> 8, nloc = u & 255;
      bsrc[i] = wcatS + ((size_t)oct * NW1 + n0 + nloc) * 8;
      bdst[i] = 65536 + u * 16;
    }
    int aoffs[2], boffs[2];
#pragma unroll
    for (int ks = 0; ks < 2; ks++) {
      aoffs[ks] = (mw * 128 + l16) * 128 + ((ks * 4 + lh) ^ (l16 & 7)) * 16;
      boffs[ks] = 65536 + ((ks * 4 + lh) * 256 + nw * 64 + l16) * 16;
    }

    // prologue: tile 0 -> buffer 0
#pragma unroll
    for (int i = 0; i < 4; i++) gload_lds16(bsrc[i], L + bdst[i]);
#pragma unroll
    for (int j = 0; j < 4; j++) {
      lo[j] = *(const f32x4*)(asrc[j]);
      hi[j] = *(const f32x4*)(asrc[j] + 4);
    }
    asm volatile("s_waitcnt vmcnt(0)" ::: "memory");
#pragma unroll
    for (int j = 0; j < 4; j++) {
      bf16x8 v;
#pragma unroll
      for (int q = 0; q < 4; q++) { v[q] = f2bf_hw(lo[j][q]); v[q + 4] = f2bf_hw(hi[j][q]); }
      *(bf16x8*)(L + awr[j]) = v;
    }
    asm volatile("s_waitcnt lgkmcnt(0)\ns_barrier" ::: "memory");

    for (int kt = 0; kt < 32; ++kt) {
      const int c = kt & 1, nc = c ^ 1;
      if (kt < 31) {
#pragma unroll
        for (int i = 0; i < 4; i++)
          gload_lds16(bsrc[i] + (size_t)(kt + 1) * bks, L + nc * 32768 + bdst[i]);
#pragma unroll
        for (int j = 0; j < 4; j++) {
          lo[j] = *(const f32x4*)(asrc[j] + (kt + 1) * 64);
          hi[j] = *(const f32x4*)(asrc[j] + (kt + 1) * 64 + 4);
        }
      }
      __builtin_amdgcn_s_setprio(1);
#pragma unroll
      for (int ks = 0; ks < 2; ks++) {
        bf16x8 b[4];
#pragma unroll
        for (int j = 0; j < 4; j++)
          b[j] = *(const bf16x8*)(L + c * 32768 + boffs[ks] + j * 256);
#pragma unroll
        for (int m = 0; m < 8; m++) {
          bf16x8 a = *(const bf16x8*)(L + c * 32768 + aoffs[ks] + m * 2048);
#pragma unroll
          for (int j = 0; j < 4; j++) acc[m][j] = mfma16(a, b[j], acc[m][j]);
        }
      }
      __builtin_amdgcn_s_setprio(0);
      if (kt < 31) {
        asm volatile("s_waitcnt vmcnt(0)" ::: "memory");
#pragma unroll
        for (int j = 0; j < 4; j++) {
          bf16x8 v;
#pragma unroll
          for (int q = 0; q < 4; q++) { v[q] = f2bf_hw(lo[j][q]); v[q + 4] = f2bf_hw(hi[j][q]); }
          *(bf16x8*)(L + nc * 32768 + awr[j]) = v;
        }
        asm volatile("s_waitcnt lgkmcnt(0)\ns_barrier" ::: "memory");
      }
    }

#pragma unroll
    for (int j = 0; j < 4; j++) {
      const int col = n0 + nw * 64 + j * 16 + l16;   // always < 512
      const float bias = b1[col];
#pragma unroll
      for (int m = 0; m < 8; m++) {
        const int row = m0 + mw * 128 + m * 16 + lh * 4;
#pragma unroll
        for (int rr = 0; rr < 4; rr++) {
          float v = acc[m][j][rr] + bias;
          v = v > 0.f ? v : 0.f;
          h1[(size_t)(row + rr) * HID + col] = f2bf(v);
        }
      }
    }
  } else {
    // ================= path B: 256x128 (jump cols), wave 64x64, acc 4x4 ======
    const int mw2 = w >> 1, nw2 = w & 1;

    f32x4 acc[4][4];
#pragma unroll
    for (int m = 0; m < 4; m++)
#pragma unroll
      for (int j = 0; j < 4; j++) acc[m][j] = (f32x4){0.f, 0.f, 0.f, 0.f};

    // B: 1024 16B-units (16KB/buf): u = i*512+tid -> oct=u>>7, nloc=u&127
    const short* bsrcB[2];
    int bdstB[2];
#pragma unroll
    for (int i = 0; i < 2; i++) {
      int u = i * 512 + tid;
      int oct = u >> 7, nloc = u & 127;
      bsrcB[i] = wcatS + ((size_t)oct * NW1 + 512 + nloc) * 8;
      bdstB[i] = 65536 + u * 16;
    }
    int aoffB[2], boffB[2];
#pragma unroll
    for (int ks = 0; ks < 2; ks++) {
      aoffB[ks] = (mw2 * 64 + l16) * 128 + ((ks * 4 + lh) ^ (l16 & 7)) * 16;
      boffB[ks] = 65536 + ((ks * 4 + lh) * 128 + nw2 * 64 + l16) * 16;
    }

    // prologue
#pragma unroll
    for (int i = 0; i < 2; i++) gload_lds16(bsrcB[i], L + bdstB[i]);
#pragma unroll
    for (int j = 0; j < 4; j++) {
      lo[j] = *(const f32x4*)(asrc[j]);
      hi[j] = *(const f32x4*)(asrc[j] + 4);
    }
    asm volatile("s_waitcnt vmcnt(0)" ::: "memory");
#pragma unroll
    for (int j = 0; j < 4; j++) {
      bf16x8 v;
#pragma unroll
      for (int q = 0; q < 4; q++) { v[q] = f2bf_hw(lo[j][q]); v[q + 4] = f2bf_hw(hi[j][q]); }
      *(bf16x8*)(L + awr[j]) = v;
    }
    asm volatile("s_waitcnt lgkmcnt(0)\ns_barrier" ::: "memory");

    for (int kt = 0; kt < 32; ++kt) {
      const int c = kt & 1, nc = c ^ 1;
      if (kt < 31) {
#pragma unroll
        for (int i = 0; i < 2; i++)
          gload_lds16(bsrcB[i] + (size_t)(kt + 1) * bks, L + nc * 32768 + bdstB[i]);
#pragma unroll
        for (int j = 0; j < 4; j++) {
          lo[j] = *(const f32x4*)(asrc[j] + (kt + 1) * 64);
          hi[j] = *(const f32x4*)(asrc[j] + (kt + 1) * 64 + 4);
        }
      }
      __builtin_amdgcn_s_setprio(1);
#pragma unroll
      for (int ks = 0; ks < 2; ks++) {
        bf16x8 b[4];
#pragma unroll
        for (int j = 0; j < 4; j++)
          b[j] = *(const bf16x8*)(L + c * 32768 + boffB[ks] + j * 256);
#pragma unroll
        for (int m = 0; m < 4; m++) {
          bf16x8 a = *(const bf16x8*)(L + c * 32768 + aoffB[ks] + m * 2048);
#pragma unroll
          for (int j = 0; j < 4; j++) acc[m][j] = mfma16(a, b[j], acc[m][j]);
        }
      }
      __builtin_amdgcn_s_setprio(0);
      if (kt < 31) {
        asm volatile("s_waitcnt vmcnt(0)" ::: "memory");
#pragma unroll
        for (int j = 0; j < 4; j++) {
          bf16x8 v;
#pragma unroll
          for (int q = 0; q < 4; q++) { v[q] = f2bf_hw(lo[j][q]); v[q + 4] = f2bf_hw(hi[j][q]); }
          *(bf16x8*)(L + nc * 32768 + awr[j]) = v;
        }
        asm volatile("s_waitcnt lgkmcnt(0)\ns_barrier" ::: "memory");
      }
    }

#pragma unroll
    for (int j = 0; j < 4; j++) {
      const int cj = nw2 * 64 + j * 16 + l16;        // 0..127
      const float bias = b3[cj] + bj[cj];
#pragma unroll
      for (int m = 0; m < 4; m++) {
        const int row = m0 + mw2 * 64 + m * 16 + lh * 4;
#pragma unroll
        for (int rr = 0; rr < 4; rr++)
          jmp[(size_t)(row + rr) * OUTD + cj] = f2bf(acc[m][j][rr] + bias);
      }
    }
  }
}

// ---- K2 (round-14 verbatim): 256x256/BK=64; both operands gload_lds dbuf;
// one wait+barrier per K-tile, stages issued post-barrier.
__global__ __launch_bounds__(512, 1) void k2(
    const short* __restrict__ h1, const short* __restrict__ w2tS,
    const float* __restrict__ b2, short* __restrict__ h2) {
  __shared__ __align__(16) char L[131072];
  const int tid = threadIdx.x;
  const int lane = tid & 63, w = tid >> 6;
  const int l16 = lane & 15, lh = lane >> 4;
  const int mw = w >> 2, nw = w & 3;
  const int bid = blockIdx.x;
  const int r = bid >> 4, w16 = bid & 15, nt = w16 >> 3, x = w16 & 7;
  const int s = r * 8 + x;
  if (s >= NS256) return;
  const int m0 = s * 256, n0 = nt * 256;

  f32x4 acc[8][4];
#pragma unroll
  for (int m = 0; m < 8; m++)
#pragma unroll
    for (int j = 0; j < 4; j++) acc[m][j] = (f32x4){0.f, 0.f, 0.f, 0.f};

  const short* asrc[4];
  const short* bsrc[4];
  int adst[4], bdst[4];
#pragma unroll
  for (int i = 0; i < 4; i++) {
    int u = i * 512 + tid;
    int oct = u >> 8, v = u & 255;
    asrc[i] = h1 + (size_t)(m0 + v) * HID + oct * 8;
    bsrc[i] = w2tS + ((size_t)oct * 512 + n0 + v) * 8;
    adst[i] = u * 16;
    bdst[i] = 65536 + u * 16;
  }
  const size_t bkstride = (size_t)8 * 512 * 8;

  int aoffs[2], boffs[2];
#pragma unroll
  for (int ks = 0; ks < 2; ks++) {
    aoffs[ks] = ((ks * 4 + lh) * 256 + mw * 128 + l16) * 16;
    boffs[ks] = 65536 + ((ks * 4 + lh) * 256 + nw * 64 + l16) * 16;
  }

#pragma unroll
  for (int i = 0; i < 4; i++) {
    gload_lds16(asrc[i], L + adst[i]);
    gload_lds16(bsrc[i], L + bdst[i]);
  }

  for (int kt = 0; kt < 8; ++kt) {
    const int c = kt & 1, nc = c ^ 1;
    asm volatile("s_waitcnt vmcnt(0) lgkmcnt(0)" ::: "memory");
    __builtin_amdgcn_s_barrier();
    if (kt < 7) {
#pragma unroll
      for (int i = 0; i < 4; i++) {
        gload_lds16(asrc[i] + (kt + 1) * 64, L + nc * 32768 + adst[i]);
        gload_lds16(bsrc[i] + (size_t)(kt + 1) * bkstride, L + nc * 32768 + bdst[i]);
      }
    }
    __builtin_amdgcn_s_setprio(1);
#pragma unroll
    for (int ks = 0; ks < 2; ks++) {
      bf16x8 b[4];
#pragma unroll
      for (int j = 0; j < 4; j++)
        b[j] = *(const bf16x8*)(L + c * 32768 + boffs[ks] + j * 256);
#pragma unroll
      for (int m = 0; m < 8; m++) {
        bf16x8 a = *(const bf16x8*)(L + c * 32768 + aoffs[ks] + m * 256);
#pragma unroll
        for (int j = 0; j < 4; j++) acc[m][j] = mfma16(a, b[j], acc[m][j]);
      }
    }
    __builtin_amdgcn_s_setprio(0);
  }

#pragma unroll
  for (int j = 0; j < 4; j++) {
    const int col = n0 + nw * 64 + j * 16 + l16;
    const float bias = b2[col];
#pragma unroll
    for (int m = 0; m < 8; m++) {
      const int row = m0 + mw * 128 + m * 16 + lh * 4;
#pragma unroll
      for (int rr = 0; rr < 4; rr++) {
        float v = acc[m][j][rr] + bias;
        v = v > 0.f ? v : 0.f;
        h2[(size_t)(row + rr) * HID + col] = f2bf(v);
      }
    }
  }
}

// ---------------- K3 (round-14 verbatim): l_enc + res-GEMM + JS loss ----------
__global__ __launch_bounds__(256, 2) void k3(
    const short* __restrict__ h2, const short* __restrict__ w3t,
    const short* __restrict__ jmp, const short* __restrict__ genc,
    const int* __restrict__ gid, float* __restrict__ partials) {
  __shared__ __align__(16) short As[128 * 32];
  __shared__ __align__(16) short Bs[128 * 32];
  __shared__ __align__(16) short Ll[128 * 128];
  __shared__ int gids[128];
  __shared__ float sred[8];
  const int mt = blockIdx.x;
  const int m0 = mt * 128;
  const int tid = threadIdx.x;
  const int lane = tid & 63, wid = tid >> 6;
  const int wr = wid >> 1, wc = wid & 1;
  const int l16 = lane & 15, lh = lane >> 4;

  if (tid < 128) {
    int r = m0 + tid;
    gids[tid] = (r < N_NODES) ? gid[r] : -1;
  }

  f32x4 acc[4][4];
#pragma unroll
  for (int i = 0; i < 4; i++)
#pragma unroll
    for (int j = 0; j < 4; j++) acc[i][j] = (f32x4){0.f, 0.f, 0.f, 0.f};

  const short* ap0 = h2 + (size_t)(m0 + (tid >> 2)) * HID + (tid & 3) * 8;
  const short* ap1 = ap0 + (size_t)64 * HID;
  const short* bp0 = w3t + (size_t)(tid >> 2) * HID + (tid & 3) * 8;
  const short* bp1 = bp0 + (size_t)64 * HID;

  for (int kt = 0; kt < HID / 32; ++kt) {
    __syncthreads();
    gload_lds16(ap0 + kt * 32, &As[tid * 8]);
    gload_lds16(ap1 + kt * 32, &As[tid * 8 + 2048]);
    gload_lds16(bp0 + kt * 32, &Bs[tid * 8]);
    gload_lds16(bp1 + kt * 32, &Bs[tid * 8 + 2048]);
    __syncthreads();
    bf16x8 a[4], b[4];
#pragma unroll
    for (int i = 0; i < 4; i++)
      a[i] = *(const bf16x8*)(&As[(wr * 64 + i * 16 + l16) * 32 + lh * 8]);
#pragma unroll
    for (int j = 0; j < 4; j++)
      b[j] = *(const bf16x8*)(&Bs[(wc * 64 + j * 16 + l16) * 32 + lh * 8]);
#pragma unroll
    for (int i = 0; i < 4; i++)
#pragma unroll
      for (int j = 0; j < 4; j++) acc[i][j] = mfma16(a[i], b[j], acc[i][j]);
  }

#pragma unroll
  for (int j = 0; j < 4; j++) {
    const int col = wc * 64 + j * 16 + l16;
#pragma unroll
    for (int i = 0; i < 4; i++) {
      const int rowb = wr * 64 + i * 16 + lh * 4;
#pragma unroll
      for (int r = 0; r < 4; r++) {
        const int row = rowb + r;
        float v = acc[i][j][r] + bf2f(jmp[(size_t)(m0 + row) * OUTD + col]);
        unsigned byte = (unsigned)row * 256u +
                        (((unsigned)col * 2u) ^ (((unsigned)(row & 7)) << 4));
        *(short*)((char*)Ll + byte) = f2bf(v);
      }
    }
  }
  __syncthreads();

  int myg[4][4];
#pragma unroll
  for (int i = 0; i < 4; i++)
#pragma unroll
    for (int r = 0; r < 4; r++) myg[i][r] = gids[wr * 64 + i * 16 + lh * 4 + r];

  float pacc = 0.f, nacc = 0.f;
  for (int nc = 0; nc < 4; ++nc) {
    f32x4 a2[4][4];
#pragma unroll
    for (int i = 0; i < 4; i++)
#pragma unroll
      for (int j = 0; j < 4; j++) a2[i][j] = (f32x4){0.f, 0.f, 0.f, 0.f};
#pragma unroll
    for (int ks = 0; ks < 4; ++ks) {
      bf16x8 af[4], bg[4];
#pragma unroll
      for (int i = 0; i < 4; i++) {
        const int row = wr * 64 + i * 16 + l16;
        unsigned byte = (unsigned)row * 256u +
                        (((unsigned)(ks * 64 + lh * 16)) ^ (((unsigned)(row & 7)) << 4));
        af[i] = *(const bf16x8*)((const char*)Ll + byte);
      }
#pragma unroll
      for (int j = 0; j < 4; j++) {
        const int g = nc * 128 + wc * 64 + j * 16 + l16;
        bg[j] = *(const bf16x8*)(genc + (size_t)g * OUTD + ks * 32 + lh * 8);
      }
#pragma unroll
      for (int i = 0; i < 4; i++)
#pragma unroll
        for (int j = 0; j < 4; j++) a2[i][j] = mfma16(af[i], bg[j], a2[i][j]);
    }
#pragma unroll
    for (int j = 0; j < 4; j++) {
      const int g = nc * 128 + wc * 64 + j * 16 + l16;
#pragma unroll
      for (int i = 0; i < 4; i++) {
#pragma unroll
        for (int r = 0; r < 4; r++) {
          float rv = a2[i][j][r];
          int gr = myg[i][r];
          float t = __expf(-fabsf(rv));
          float lg = __logf(1.f + t);
          if (gr == g)
            pacc += LOG2F_ - (fmaxf(-rv, 0.f) + lg);
          else if (gr >= 0)
            nacc += (fmaxf(rv, 0.f) + lg) - LOG2F_;
        }
      }
    }
  }

#pragma unroll
  for (int o = 32; o; o >>= 1) {
    pacc += __shfl_down(pacc, o);
    nacc += __shfl_down(nacc, o);
  }
  if (lane == 0) { sred[wid] = pacc; sred[4 + wid] = nacc; }
  __syncthreads();
  if (tid == 0) {
    partials[2 * mt] = sred[0] + sred[1] + sred[2] + sred[3];
    partials[2 * mt + 1] = sred[4] + sred[5] + sred[6] + sred[7];
  }
}

// ---------------- K4: deterministic final reduction ---------------------------
__global__ void k4(const float* __restrict__ partials, float* __restrict__ out) {
  const int tid = threadIdx.x;
  float p = 0.f, n = 0.f;
  for (int i = tid; i < MT; i += 256) {
    p += partials[2 * i];
    n += partials[2 * i + 1];
  }
#pragma unroll
  for (int o = 32; o; o >>= 1) {
    p += __shfl_down(p, o);
    n += __shfl_down(n, o);
  }
  __shared__ float sp[4], sn[4];
  const int wid = tid >> 6, lane = tid & 63;
  if (lane == 0) { sp[wid] = p; sn[wid] = n; }
  __syncthreads();
  if (tid == 0) {
    float P = sp[0] + sp[1] + sp[2] + sp[3];
    float Nn = sn[0] + sn[1] + sn[2] + sn[3];
    out[0] = Nn / (100000.0f * 511.0f) - P / 100000.0f;
  }
}

extern "C" void kernel_launch(void* const* d_in, const int* in_sizes, int n_in,
                              void* d_out, int out_size, void* d_ws, size_t ws_size,
                              hipStream_t stream) {
  const float* feat = (const float*)d_in[0];
  const float* genc_f = (const float*)d_in[1];
  const int* gid = (const int*)d_in[2];
  const float* W1 = (const float*)d_in[3];
  const float* b1 = (const float*)d_in[4];
  const float* W2 = (const float*)d_in[5];
  const float* b2 = (const float*)d_in[6];
  const float* W3 = (const float*)d_in[7];
  const float* b3 = (const float*)d_in[8];
  const float* Wj = (const float*)d_in[9];
  const float* bj = (const float*)d_in[10];
  float* out = (float*)d_out;

  char* ws = (char*)d_ws;
  float* partials = (float*)ws;                       // 782*2 f32
  short* wcatS = (short*)(ws + 8192);                 // [256][640][8] k-slot
  short* w2tS = wcatS + (size_t)256 * NW1 * 8;        // [64][512][8] k-slot
  short* w3t = w2tS + (size_t)64 * 512 * 8;           // [128][512] row-major
  short* gencb = w3t + (size_t)128 * 512;             // [512][128] row-major
  short* h1 = gencb + (size_t)512 * 128;              // [MPAD][512]
  short* h2 = h1 + (size_t)MPAD * 512;                // [MPAD][512]
  short* jmp = h2 + (size_t)MPAD * 512;               // [MPAD][128]

  kprep<<<6656, 256, 0, stream>>>(W1, Wj, W2, W3, genc_f, wcatS, w2tS, w3t, gencb);
  k1<<<49 * 24, 512, 0, stream>>>(feat, wcatS, b1, b3, bj, h1, jmp);
  k2<<<49 * 16, 512, 0, stream>>>(h1, w2tS, b2, h2);
  k3<<<MT, 256, 0, stream>>>(h2, w3t, jmp, gencb, gid, partials);
  k4<<<1, 256, 0, stream>>>(partials, out);
}

// Round 19
// 617.839 us; speedup vs baseline: 1.2160x; 1.0030x over previous
//
#include <hip/hip_runtime.h>
#include <hip/hip_bf16.h>
#include <stdint.h>

#define N_NODES 100000
#define MT      782          // 128-row tiles (k3)
#define NS256   391          // 256-row stripes (k1,k2)
#define MPAD    (MT*128)     // 100096 = 391*256
#define IN_DIM  2048
#define HID     512
#define OUTD    128
#define NG      512
#define NW1     640          // k1 B width (512 + 128, no pad)
#define LOG2F_  0.69314718055994531f

typedef __attribute__((ext_vector_type(4))) float f32x4;
typedef __attribute__((ext_vector_type(8))) short bf16x8;

typedef const __attribute__((address_space(1))) unsigned int gas_u32;
typedef __attribute__((address_space(3))) unsigned int las_u32;

__device__ __forceinline__ void gload_lds16(const void* g, void* lds) {
  __builtin_amdgcn_global_load_lds((gas_u32*)g, (las_u32*)lds, 16, 0, 0);
}

__device__ __forceinline__ short f2bf(float f) {   // manual RNE
  unsigned u = __builtin_bit_cast(unsigned, f);
  u = (u + 0x7fffu + ((u >> 16) & 1u)) >> 16;
  return (short)u;
}
__device__ __forceinline__ short f2bf_hw(float f) {
  __hip_bfloat16 h = __float2bfloat16(f);
  return __builtin_bit_cast(short, h);
}
__device__ __forceinline__ float bf2f(short s) {
  unsigned u = ((unsigned)(unsigned short)s) << 16;
  return __builtin_bit_cast(float, u);
}

__device__ __forceinline__ f32x4 mfma16(bf16x8 a, bf16x8 b, f32x4 c) {
  return __builtin_amdgcn_mfma_f32_16x16x32_bf16(a, b, c, 0, 0, 0);
}

// ---------------- prep (coalesced: consecutive threads -> consecutive n) ------
// wcatS: k-slot [k/8][640][e] ([W1 | Wj], no padding).
// w2tS : k-slot [k/8][512][e].  w3t: row-major [n][k].  gencb: row-major [g][k].
__global__ void kprep(const float* __restrict__ W1, const float* __restrict__ Wj,
                      const float* __restrict__ W2, const float* __restrict__ W3,
                      const float* __restrict__ ge,
                      short* __restrict__ wcatS, short* __restrict__ w2tS,
                      short* __restrict__ w3t, short* __restrict__ gencb) {
  const int SW1 = 2048 * 512, SWj = 2048 * 128;
  const int SW2 = 512 * 512, SW3 = 128 * 512, SGE = 512 * 128;
  int t = blockIdx.x * 256 + threadIdx.x;
  if (t < SW1) {
    int n = t & 511, k = t >> 9;
    wcatS[(((size_t)(k >> 3)) * NW1 + n) * 8 + (k & 7)] = f2bf(W1[(size_t)k * 512 + n]);
    return;
  }
  t -= SW1;
  if (t < SWj) {
    int n = t & 127, k = t >> 7;
    wcatS[(((size_t)(k >> 3)) * NW1 + 512 + n) * 8 + (k & 7)] = f2bf(Wj[(size_t)k * 128 + n]);
    return;
  }
  t -= SWj;
  if (t < SW2) {
    int n = t & 511, k = t >> 9;
    w2tS[(((size_t)(k >> 3)) * 512 + n) * 8 + (k & 7)] = f2bf(W2[(size_t)k * 512 + n]);
    return;
  }
  t -= SW2;
  if (t < SW3) {
    int n = t & 127, k = t >> 7;
    w3t[(size_t)n * 512 + k] = f2bf(W3[(size_t)k * 128 + n]);
    return;
  }
  t -= SW3;
  if (t < SGE) gencb[t] = f2bf(ge[t]);
}

// ---- K1 (round-18 verbatim): dual-geometry, no padded columns.
// nt<2 : 256x256 tile, wave 128x64 (2Mx4N), acc 8x4, cols nt*256.
// nt==2: 256x128 tile, wave 64x64 (4Mx2N), acc 4x4, cols 512..639 -> jump.
// Both: BK=64, single barrier + single vmcnt(0) per K-tile AFTER the MFMA
// cluster; A (f32) reg-staged -> cvt -> XOR-swizzled ds_write; B via gload_lds.
// Grid: bid = r*24 + nt*8 + x, stripe s = r*8+x -> 3 nt-siblings on same XCD.
__global__ __launch_bounds__(512, 1) void k1(
    const float* __restrict__ feat, const short* __restrict__ wcatS,
    const float* __restrict__ b1, const float* __restrict__ b3,
    const float* __restrict__ bj,
    short* __restrict__ h1, short* __restrict__ jmp) {
  __shared__ __align__(16) char L[131072];  // A dbuf 2x32KB @0 (oct-swz), B dbuf 2x32KB @65536 (linear)
  const int tid = threadIdx.x;
  const int lane = tid & 63, w = tid >> 6;
  const int l16 = lane & 15, lh = lane >> 4;
  const int bid = blockIdx.x;
  const int r = bid / 24, w24 = bid - r * 24, nt = w24 >> 3, x = w24 & 7;
  const int s = r * 8 + x;
  if (s >= NS256) return;
  const int m0 = s * 256;

  const int aoct = tid & 7;
  const int arow0 = tid >> 3;
  const int aoctw = aoct ^ (arow0 & 7);
  const float* asrc[4];
  int awr[4];
#pragma unroll
  for (int j = 0; j < 4; j++) {
    int rowg = m0 + arow0 + j * 64;
    if (rowg >= N_NODES) rowg = N_NODES - 1;  // clamp; masked via gid=-1 in k3
    asrc[j] = feat + (size_t)rowg * IN_DIM + aoct * 8;
    awr[j] = (arow0 + j * 64) * 128 + aoctw * 16;
  }
  const size_t bks = (size_t)8 * NW1 * 8;  // shorts per K-tile in wcatS
  f32x4 lo[4], hi[4];

  if (nt < 2) {
    // ================= path A: 256x256, wave 128x64, acc 8x4 =================
    const int mw = w >> 2, nw = w & 3;
    const int n0 = nt * 256;

    f32x4 acc[8][4];
#pragma unroll
    for (int m = 0; m < 8; m++)
#pragma unroll
      for (int j = 0; j < 4; j++) acc[m][j] = (f32x4){0.f, 0.f, 0.f, 0.f};

    const short* bsrc[4];
    int bdst[4];
#pragma unroll
    for (int i = 0; i < 4; i++) {
      int u = i * 512 + tid;
      int oct = u >> 8, nloc = u & 255;
      bsrc[i] = wcatS + ((size_t)oct * NW1 + n0 + nloc) * 8;
      bdst[i] = 65536 + u * 16;
    }
    int aoffs[2], boffs[2];
#pragma unroll
    for (int ks = 0; ks < 2; ks++) {
      aoffs[ks] = (mw * 128 + l16) * 128 + ((ks * 4 + lh) ^ (l16 & 7)) * 16;
      boffs[ks] = 65536 + ((ks * 4 + lh) * 256 + nw * 64 + l16) * 16;
    }

#pragma unroll
    for (int i = 0; i < 4; i++) gload_lds16(bsrc[i], L + bdst[i]);
#pragma unroll
    for (int j = 0; j < 4; j++) {
      lo[j] = *(const f32x4*)(asrc[j]);
      hi[j] = *(const f32x4*)(asrc[j] + 4);
    }
    asm volatile("s_waitcnt vmcnt(0)" ::: "memory");
#pragma unroll
    for (int j = 0; j < 4; j++) {
      bf16x8 v;
#pragma unroll
      for (int q = 0; q < 4; q++) { v[q] = f2bf_hw(lo[j][q]); v[q + 4] = f2bf_hw(hi[j][q]); }
      *(bf16x8*)(L + awr[j]) = v;
    }
    asm volatile("s_waitcnt lgkmcnt(0)\ns_barrier" ::: "memory");

    for (int kt = 0; kt < 32; ++kt) {
      const int c = kt & 1, nc = c ^ 1;
      if (kt < 31) {
#pragma unroll
        for (int i = 0; i < 4; i++)
          gload_lds16(bsrc[i] + (size_t)(kt + 1) * bks, L + nc * 32768 + bdst[i]);
#pragma unroll
        for (int j = 0; j < 4; j++) {
          lo[j] = *(const f32x4*)(asrc[j] + (kt + 1) * 64);
          hi[j] = *(const f32x4*)(asrc[j] + (kt + 1) * 64 + 4);
        }
      }
      __builtin_amdgcn_s_setprio(1);
#pragma unroll
      for (int ks = 0; ks < 2; ks++) {
        bf16x8 b[4];
#pragma unroll
        for (int j = 0; j < 4; j++)
          b[j] = *(const bf16x8*)(L + c * 32768 + boffs[ks] + j * 256);
#pragma unroll
        for (int m = 0; m < 8; m++) {
          bf16x8 a = *(const bf16x8*)(L + c * 32768 + aoffs[ks] + m * 2048);
#pragma unroll
          for (int j = 0; j < 4; j++) acc[m][j] = mfma16(a, b[j], acc[m][j]);
        }
      }
      __builtin_amdgcn_s_setprio(0);
      if (kt < 31) {
        asm volatile("s_waitcnt vmcnt(0)" ::: "memory");
#pragma unroll
        for (int j = 0; j < 4; j++) {
          bf16x8 v;
#pragma unroll
          for (int q = 0; q < 4; q++) { v[q] = f2bf_hw(lo[j][q]); v[q + 4] = f2bf_hw(hi[j][q]); }
          *(bf16x8*)(L + nc * 32768 + awr[j]) = v;
        }
        asm volatile("s_waitcnt lgkmcnt(0)\ns_barrier" ::: "memory");
      }
    }

#pragma unroll
    for (int j = 0; j < 4; j++) {
      const int col = n0 + nw * 64 + j * 16 + l16;   // always < 512
      const float bias = b1[col];
#pragma unroll
      for (int m = 0; m < 8; m++) {
        const int row = m0 + mw * 128 + m * 16 + lh * 4;
#pragma unroll
        for (int rr = 0; rr < 4; rr++) {
          float v = acc[m][j][rr] + bias;
          v = v > 0.f ? v : 0.f;
          h1[(size_t)(row + rr) * HID + col] = f2bf(v);
        }
      }
    }
  } else {
    // ================= path B: 256x128 (jump cols), wave 64x64, acc 4x4 ======
    const int mw2 = w >> 1, nw2 = w & 1;

    f32x4 acc[4][4];
#pragma unroll
    for (int m = 0; m < 4; m++)
#pragma unroll
      for (int j = 0; j < 4; j++) acc[m][j] = (f32x4){0.f, 0.f, 0.f, 0.f};

    const short* bsrcB[2];
    int bdstB[2];
#pragma unroll
    for (int i = 0; i < 2; i++) {
      int u = i * 512 + tid;
      int oct = u >> 7, nloc = u & 127;
      bsrcB[i] = wcatS + ((size_t)oct * NW1 + 512 + nloc) * 8;
      bdstB[i] = 65536 + u * 16;
    }
    int aoffB[2], boffB[2];
#pragma unroll
    for (int ks = 0; ks < 2; ks++) {
      aoffB[ks] = (mw2 * 64 + l16) * 128 + ((ks * 4 + lh) ^ (l16 & 7)) * 16;
      boffB[ks] = 65536 + ((ks * 4 + lh) * 128 + nw2 * 64 + l16) * 16;
    }

#pragma unroll
    for (int i = 0; i < 2; i++) gload_lds16(bsrcB[i], L + bdstB[i]);
#pragma unroll
    for (int j = 0; j < 4; j++) {
      lo[j] = *(const f32x4*)(asrc[j]);
      hi[j] = *(const f32x4*)(asrc[j] + 4);
    }
    asm volatile("s_waitcnt vmcnt(0)" ::: "memory");
#pragma unroll
    for (int j = 0; j < 4; j++) {
      bf16x8 v;
#pragma unroll
      for (int q = 0; q < 4; q++) { v[q] = f2bf_hw(lo[j][q]); v[q + 4] = f2bf_hw(hi[j][q]); }
      *(bf16x8*)(L + awr[j]) = v;
    }
    asm volatile("s_waitcnt lgkmcnt(0)\ns_barrier" ::: "memory");

    for (int kt = 0; kt < 32; ++kt) {
      const int c = kt & 1, nc = c ^ 1;
      if (kt < 31) {
#pragma unroll
        for (int i = 0; i < 2; i++)
          gload_lds16(bsrcB[i] + (size_t)(kt + 1) * bks, L + nc * 32768 + bdstB[i]);
#pragma unroll
        for (int j = 0; j < 4; j++) {
          lo[j] = *(const f32x4*)(asrc[j] + (kt + 1) * 64);
          hi[j] = *(const f32x4*)(asrc[j] + (kt + 1) * 64 + 4);
        }
      }
      __builtin_amdgcn_s_setprio(1);
#pragma unroll
      for (int ks = 0; ks < 2; ks++) {
        bf16x8 b[4];
#pragma unroll
        for (int j = 0; j < 4; j++)
          b[j] = *(const bf16x8*)(L + c * 32768 + boffB[ks] + j * 256);
#pragma unroll
        for (int m = 0; m < 4; m++) {
          bf16x8 a = *(const bf16x8*)(L + c * 32768 + aoffB[ks] + m * 2048);
#pragma unroll
          for (int j = 0; j < 4; j++) acc[m][j] = mfma16(a, b[j], acc[m][j]);
        }
      }
      __builtin_amdgcn_s_setprio(0);
      if (kt < 31) {
        asm volatile("s_waitcnt vmcnt(0)" ::: "memory");
#pragma unroll
        for (int j = 0; j < 4; j++) {
          bf16x8 v;
#pragma unroll
          for (int q = 0; q < 4; q++) { v[q] = f2bf_hw(lo[j][q]); v[q + 4] = f2bf_hw(hi[j][q]); }
          *(bf16x8*)(L + nc * 32768 + awr[j]) = v;
        }
        asm volatile("s_waitcnt lgkmcnt(0)\ns_barrier" ::: "memory");
      }
    }

#pragma unroll
    for (int j = 0; j < 4; j++) {
      const int cj = nw2 * 64 + j * 16 + l16;        // 0..127
      const float bias = b3[cj] + bj[cj];
#pragma unroll
      for (int m = 0; m < 4; m++) {
        const int row = m0 + mw2 * 64 + m * 16 + lh * 4;
#pragma unroll
        for (int rr = 0; rr < 4; rr++)
          jmp[(size_t)(row + rr) * OUTD + cj] = f2bf(acc[m][j][rr] + bias);
      }
    }
  }
}

// ---- K2 (round-14/18 verbatim): 256x256/BK=64; both operands gload_lds dbuf;
// one wait+barrier per K-tile, stages issued post-barrier.
__global__ __launch_bounds__(512, 1) void k2(
    const short* __restrict__ h1, const short* __restrict__ w2tS,
    const float* __restrict__ b2, short* __restrict__ h2) {
  __shared__ __align__(16) char L[131072];
  const int tid = threadIdx.x;
  const int lane = tid & 63, w = tid >> 6;
  const int l16 = lane & 15, lh = lane >> 4;
  const int mw = w >> 2, nw = w & 3;
  const int bid = blockIdx.x;
  const int r = bid >> 4, w16 = bid & 15, nt = w16 >> 3, x = w16 & 7;
  const int s = r * 8 + x;
  if (s >= NS256) return;
  const int m0 = s * 256, n0 = nt * 256;

  f32x4 acc[8][4];
#pragma unroll
  for (int m = 0; m < 8; m++)
#pragma unroll
    for (int j = 0; j < 4; j++) acc[m][j] = (f32x4){0.f, 0.f, 0.f, 0.f};

  const short* asrc[4];
  const short* bsrc[4];
  int adst[4], bdst[4];
#pragma unroll
  for (int i = 0; i < 4; i++) {
    int u = i * 512 + tid;
    int oct = u >> 8, v = u & 255;
    asrc[i] = h1 + (size_t)(m0 + v) * HID + oct * 8;
    bsrc[i] = w2tS + ((size_t)oct * 512 + n0 + v) * 8;
    adst[i] = u * 16;
    bdst[i] = 65536 + u * 16;
  }
  const size_t bkstride = (size_t)8 * 512 * 8;

  int aoffs[2], boffs[2];
#pragma unroll
  for (int ks = 0; ks < 2; ks++) {
    aoffs[ks] = ((ks * 4 + lh) * 256 + mw * 128 + l16) * 16;
    boffs[ks] = 65536 + ((ks * 4 + lh) * 256 + nw * 64 + l16) * 16;
  }

#pragma unroll
  for (int i = 0; i < 4; i++) {
    gload_lds16(asrc[i], L + adst[i]);
    gload_lds16(bsrc[i], L + bdst[i]);
  }

  for (int kt = 0; kt < 8; ++kt) {
    const int c = kt & 1, nc = c ^ 1;
    asm volatile("s_waitcnt vmcnt(0) lgkmcnt(0)" ::: "memory");
    __builtin_amdgcn_s_barrier();
    if (kt < 7) {
#pragma unroll
      for (int i = 0; i < 4; i++) {
        gload_lds16(asrc[i] + (kt + 1) * 64, L + nc * 32768 + adst[i]);
        gload_lds16(bsrc[i] + (size_t)(kt + 1) * bkstride, L + nc * 32768 + bdst[i]);
      }
    }
    __builtin_amdgcn_s_setprio(1);
#pragma unroll
    for (int ks = 0; ks < 2; ks++) {
      bf16x8 b[4];
#pragma unroll
      for (int j = 0; j < 4; j++)
        b[j] = *(const bf16x8*)(L + c * 32768 + boffs[ks] + j * 256);
#pragma unroll
      for (int m = 0; m < 8; m++) {
        bf16x8 a = *(const bf16x8*)(L + c * 32768 + aoffs[ks] + m * 256);
#pragma unroll
        for (int j = 0; j < 4; j++) acc[m][j] = mfma16(a, b[j], acc[m][j]);
      }
    }
    __builtin_amdgcn_s_setprio(0);
  }

#pragma unroll
  for (int j = 0; j < 4; j++) {
    const int col = n0 + nw * 64 + j * 16 + l16;
    const float bias = b2[col];
#pragma unroll
    for (int m = 0; m < 8; m++) {
      const int row = m0 + mw * 128 + m * 16 + lh * 4;
#pragma unroll
      for (int rr = 0; rr < 4; rr++) {
        float v = acc[m][j][rr] + bias;
        v = v > 0.f ? v : 0.f;
        h2[(size_t)(row + rr) * HID + col] = f2bf(v);
      }
    }
  }
}

// ---- K3: GEMM phase double-buffered + issue-early (R15-verified): stages for
// kt+1 issued after the barrier, consumed next iter -> the implicit vmcnt(0)
// drain covers loads issued a full compute earlier. Phase 2 unchanged.
__global__ __launch_bounds__(256, 2) void k3(
    const short* __restrict__ h2, const short* __restrict__ w3t,
    const short* __restrict__ jmp, const short* __restrict__ genc,
    const int* __restrict__ gid, float* __restrict__ partials) {
  __shared__ __align__(16) short As[2][128 * 32];
  __shared__ __align__(16) short Bs[2][128 * 32];
  __shared__ __align__(16) short Ll[128 * 128];  // l_enc, XOR-swizzled rows
  __shared__ int gids[128];
  __shared__ float sred[8];
  const int mt = blockIdx.x;
  const int m0 = mt * 128;
  const int tid = threadIdx.x;
  const int lane = tid & 63, wid = tid >> 6;
  const int wr = wid >> 1, wc = wid & 1;
  const int l16 = lane & 15, lh = lane >> 4;

  if (tid < 128) {
    int r = m0 + tid;
    gids[tid] = (r < N_NODES) ? gid[r] : -1;
  }

  f32x4 acc[4][4];
#pragma unroll
  for (int i = 0; i < 4; i++)
#pragma unroll
    for (int j = 0; j < 4; j++) acc[i][j] = (f32x4){0.f, 0.f, 0.f, 0.f};

  const short* ap0 = h2 + (size_t)(m0 + (tid >> 2)) * HID + (tid & 3) * 8;
  const short* ap1 = ap0 + (size_t)64 * HID;
  const short* bp0 = w3t + (size_t)(tid >> 2) * HID + (tid & 3) * 8;
  const short* bp1 = bp0 + (size_t)64 * HID;

  // prologue: stage kt=0 into buf 0
  gload_lds16(ap0, &As[0][tid * 8]);
  gload_lds16(ap1, &As[0][tid * 8 + 2048]);
  gload_lds16(bp0, &Bs[0][tid * 8]);
  gload_lds16(bp1, &Bs[0][tid * 8 + 2048]);

  for (int kt = 0; kt < HID / 32; ++kt) {
    const int c = kt & 1, nc = c ^ 1;
    __syncthreads();  // drains vmcnt: stages(kt) landed (issued last iter)
    if (kt < HID / 32 - 1) {
      gload_lds16(ap0 + (kt + 1) * 32, &As[nc][tid * 8]);
      gload_lds16(ap1 + (kt + 1) * 32, &As[nc][tid * 8 + 2048]);
      gload_lds16(bp0 + (kt + 1) * 32, &Bs[nc][tid * 8]);
      gload_lds16(bp1 + (kt + 1) * 32, &Bs[nc][tid * 8 + 2048]);
    }
    bf16x8 a[4], b[4];
#pragma unroll
    for (int i = 0; i < 4; i++)
      a[i] = *(const bf16x8*)(&As[c][(wr * 64 + i * 16 + l16) * 32 + lh * 8]);
#pragma unroll
    for (int j = 0; j < 4; j++)
      b[j] = *(const bf16x8*)(&Bs[c][(wc * 64 + j * 16 + l16) * 32 + lh * 8]);
#pragma unroll
    for (int i = 0; i < 4; i++)
#pragma unroll
      for (int j = 0; j < 4; j++) acc[i][j] = mfma16(a[i], b[j], acc[i][j]);
  }
  __syncthreads();

  // epilogue: l_enc = acc + jump (jump already holds b3+bj) -> Ll (swizzled)
#pragma unroll
  for (int j = 0; j < 4; j++) {
    const int col = wc * 64 + j * 16 + l16;
#pragma unroll
    for (int i = 0; i < 4; i++) {
      const int rowb = wr * 64 + i * 16 + lh * 4;
#pragma unroll
      for (int r = 0; r < 4; r++) {
        const int row = rowb + r;
        float v = acc[i][j][r] + bf2f(jmp[(size_t)(m0 + row) * OUTD + col]);
        unsigned byte = (unsigned)row * 256u +
                        (((unsigned)col * 2u) ^ (((unsigned)(row & 7)) << 4));
        *(short*)((char*)Ll + byte) = f2bf(v);
      }
    }
  }
  __syncthreads();

  int myg[4][4];
#pragma unroll
  for (int i = 0; i < 4; i++)
#pragma unroll
    for (int r = 0; r < 4; r++) myg[i][r] = gids[wr * 64 + i * 16 + lh * 4 + r];

  float pacc = 0.f, nacc = 0.f;
  for (int nc4 = 0; nc4 < 4; ++nc4) {
    f32x4 a2[4][4];
#pragma unroll
    for (int i = 0; i < 4; i++)
#pragma unroll
      for (int j = 0; j < 4; j++) a2[i][j] = (f32x4){0.f, 0.f, 0.f, 0.f};
#pragma unroll
    for (int ks = 0; ks < 4; ++ks) {
      bf16x8 af[4], bg[4];
#pragma unroll
      for (int i = 0; i < 4; i++) {
        const int row = wr * 64 + i * 16 + l16;
        unsigned byte = (unsigned)row * 256u +
                        (((unsigned)(ks * 64 + lh * 16)) ^ (((unsigned)(row & 7)) << 4));
        af[i] = *(const bf16x8*)((const char*)Ll + byte);
      }
#pragma unroll
      for (int j = 0; j < 4; j++) {
        const int g = nc4 * 128 + wc * 64 + j * 16 + l16;
        bg[j] = *(const bf16x8*)(genc + (size_t)g * OUTD + ks * 32 + lh * 8);
      }
#pragma unroll
      for (int i = 0; i < 4; i++)
#pragma unroll
        for (int j = 0; j < 4; j++) a2[i][j] = mfma16(af[i], bg[j], a2[i][j]);
    }
#pragma unroll
    for (int j = 0; j < 4; j++) {
      const int g = nc4 * 128 + wc * 64 + j * 16 + l16;
#pragma unroll
      for (int i = 0; i < 4; i++) {
#pragma unroll
        for (int r = 0; r < 4; r++) {
          float rv = a2[i][j][r];
          int gr = myg[i][r];
          float t = __expf(-fabsf(rv));
          float lg = __logf(1.f + t);
          if (gr == g)
            pacc += LOG2F_ - (fmaxf(-rv, 0.f) + lg);
          else if (gr >= 0)
            nacc += (fmaxf(rv, 0.f) + lg) - LOG2F_;
        }
      }
    }
  }

#pragma unroll
  for (int o = 32; o; o >>= 1) {
    pacc += __shfl_down(pacc, o);
    nacc += __shfl_down(nacc, o);
  }
  if (lane == 0) { sred[wid] = pacc; sred[4 + wid] = nacc; }
  __syncthreads();
  if (tid == 0) {
    partials[2 * mt] = sred[0] + sred[1] + sred[2] + sred[3];
    partials[2 * mt + 1] = sred[4] + sred[5] + sred[6] + sred[7];
  }
}

// ---------------- K4: deterministic final reduction ---------------------------
__global__ void k4(const float* __restrict__ partials, float* __restrict__ out) {
  const int tid = threadIdx.x;
  float p = 0.f, n = 0.f;
  for (int i = tid; i < MT; i += 256) {
    p += partials[2 * i];
    n += partials[2 * i + 1];
  }
#pragma unroll
  for (int o = 32; o; o >>= 1) {
    p += __shfl_down(p, o);
    n += __shfl_down(n, o);
  }
  __shared__ float sp[4], sn[4];
  const int wid = tid >> 6, lane = tid & 63;
  if (lane == 0) { sp[wid] = p; sn[wid] = n; }
  __syncthreads();
  if (tid == 0) {
    float P = sp[0] + sp[1] + sp[2] + sp[3];
    float Nn = sn[0] + sn[1] + sn[2] + sn[3];
    out[0] = Nn / (100000.0f * 511.0f) - P / 100000.0f;
  }
}

extern "C" void kernel_launch(void* const* d_in, const int* in_sizes, int n_in,
                              void* d_out, int out_size, void* d_ws, size_t ws_size,
                              hipStream_t stream) {
  const float* feat = (const float*)d_in[0];
  const float* genc_f = (const float*)d_in[1];
  const int* gid = (const int*)d_in[2];
  const float* W1 = (const float*)d_in[3];
  const float* b1 = (const float*)d_in[4];
  const float* W2 = (const float*)d_in[5];
  const float* b2 = (const float*)d_in[6];
  const float* W3 = (const float*)d_in[7];
  const float* b3 = (const float*)d_in[8];
  const float* Wj = (const float*)d_in[9];
  const float* bj = (const float*)d_in[10];
  float* out = (float*)d_out;

  char* ws = (char*)d_ws;
  float* partials = (float*)ws;                       // 782*2 f32
  short* wcatS = (short*)(ws + 8192);                 // [256][640][8] k-slot
  short* w2tS = wcatS + (size_t)256 * NW1 * 8;        // [64][512][8] k-slot
  short* w3t = w2tS + (size_t)64 * 512 * 8;           // [128][512] row-major
  short* gencb = w3t + (size_t)128 * 512;             // [512][128] row-major
  short* h1 = gencb + (size_t)512 * 128;              // [MPAD][512]
  short* h2 = h1 + (size_t)MPAD * 512;                // [MPAD][512]
  short* jmp = h2 + (size_t)MPAD * 512;               // [MPAD][128]

  kprep<<<6656, 256, 0, stream>>>(W1, Wj, W2, W3, genc_f, wcatS, w2tS, w3t, gencb);
  k1<<<49 * 24, 512, 0, stream>>>(feat, wcatS, b1, b3, bj, h1, jmp);
  k2<<<49 * 16, 512, 0, stream>>>(h1, w2tS, b2, h2);
  k3<<<MT, 256, 0, stream>>>(h2, w3t, jmp, gencb, gid, partials);
  k4<<<1, 256, 0, stream>>>(partials, out);
}